// Round 3
// baseline (285.982 us; speedup 1.0000x reference)
//
#include <hip/hip_runtime.h>
#include <hip/hip_bf16.h>
#include <math.h>

typedef __attribute__((ext_vector_type(4))) float f32x4;
typedef __attribute__((ext_vector_type(8))) short short8;
typedef __attribute__((ext_vector_type(8))) unsigned short ushort8;

__device__ __forceinline__ unsigned short f2bf(float f) {
  __hip_bfloat16 h = __float2bfloat16(f);
  return *reinterpret_cast<unsigned short*>(&h);
}

// ---------------- RoPE angle tables (cos,sin interleaved) ----------------
// qtab: [4096][32][2], ktab: [1024][32][2]
__global__ void k_tables(float* __restrict__ qtab, float* __restrict__ ktab) {
  int idx = blockIdx.x * 256 + threadIdx.x;
  if (idx < 4096 * 32) {
    int n = idx >> 5, i = idx & 31;
    float freq = powf(10000.0f, -(float)(i >> 1) * (1.0f / 16.0f));
    float pos = (i & 1) ? (float)(n >> 6) : (float)(n & 63);
    float a = pos * freq;
    qtab[idx * 2] = cosf(a);
    qtab[idx * 2 + 1] = sinf(a);
  } else if (idx < 4096 * 32 + 1024 * 32) {
    int t = idx - 4096 * 32;
    int m = t >> 5, i = t & 31;
    float freq = powf(10000.0f, -(float)(i >> 1) * (1.0f / 16.0f));
    float pos = (i & 1) ? (0.5f + 2.0f * (float)(m >> 6)) : (0.5f + 2.0f * (float)(m & 63));
    float a = pos * freq;
    ktab[t * 2] = cosf(a);
    ktab[t * 2 + 1] = sinf(a);
  }
}

// ---------------- gather x -> A_sr (conv-as-GEMM LHS) ----------------
// A_sr[b*1024 + oh*32+ow][patch*768 + c] = x[b, (2oh+kh)*64 + 2ow+kw, c]
__global__ void k_gather(const float* __restrict__ x, float* __restrict__ asr) {
  int g = blockIdx.x * 256 + threadIdx.x;          // float4 index
  if (g >= 2048 * 768) return;                     // 2048 rows * 768 float4/row
  int row = g / 768;
  int c4 = g - row * 768;
  int patch = c4 / 192, cc = c4 - patch * 192;
  int b = row >> 10, p = row & 1023;
  int oh = p >> 5, ow = p & 31;
  int kh = patch >> 1, kw = patch & 1;
  int srcrow = b * 4096 + (2 * oh + kh) * 64 + (2 * ow + kw);
  ((float4*)asr)[g] = *((const float4*)(x + (size_t)srcrow * 768) + cc);
}

// ---------------- repack sr_w (O,C,2,2) -> (O, patch*768+c) ----------------
__global__ void k_repack(const float* __restrict__ srw, float* __restrict__ wp) {
  int g = blockIdx.x * 256 + threadIdx.x;
  if (g >= 768 * 3072) return;
  int o = g / 3072;
  int k = g - o * 3072;
  int patch = k / 768;
  int c = k - patch * 768;
  wp[g] = srw[o * 3072 + c * 4 + patch];
}

// ---------------- GEMM: C = A @ W^T (+bias), bf16 MFMA, f32 in ----------------
// 128x128 tile, BK=32, 4 waves (2x2), each wave 64x64 (4x4 frags of 16x16)
template<bool HAS_BIAS, bool OUT_BF16>
__global__ __launch_bounds__(256) void k_gemm(
    const float* __restrict__ A, const float* __restrict__ W,
    const float* __restrict__ bias, void* __restrict__ Cout,
    int M, int Nn, int K)
{
  __shared__ __align__(16) unsigned short As[128][40];   // 80B rows: 16B-aligned
  __shared__ __align__(16) unsigned short Ws[128][40];
  const int tid = threadIdx.x;
  const int lane = tid & 63;
  const int wid = tid >> 6;
  const int wr = (wid >> 1) * 64;
  const int wc = (wid & 1) * 64;
  const int l15 = lane & 15, lhi = lane >> 4;
  const int cm = blockIdx.y * 128, cn = blockIdx.x * 128;

  const int srow = tid >> 1;
  const int scol = (tid & 1) * 16;
  const float* ap = A + (size_t)(cm + srow) * K + scol;
  const float* wp = W + (size_t)(cn + srow) * K + scol;

  f32x4 zero = {0.f, 0.f, 0.f, 0.f};
  f32x4 acc[4][4];
  for (int i = 0; i < 4; i++)
    for (int j = 0; j < 4; j++) acc[i][j] = zero;

  for (int kt = 0; kt < K; kt += 32) {
    float ab[16], wb[16];
    #pragma unroll
    for (int i = 0; i < 4; i++) {
      *(float4*)&ab[i * 4] = *(const float4*)(ap + kt + i * 4);
      *(float4*)&wb[i * 4] = *(const float4*)(wp + kt + i * 4);
    }
    ushort8 av0, av1, wv0, wv1;
    #pragma unroll
    for (int e = 0; e < 8; e++) {
      av0[e] = f2bf(ab[e]); av1[e] = f2bf(ab[8 + e]);
      wv0[e] = f2bf(wb[e]); wv1[e] = f2bf(wb[8 + e]);
    }
    *(ushort8*)&As[srow][scol]     = av0;
    *(ushort8*)&As[srow][scol + 8] = av1;
    *(ushort8*)&Ws[srow][scol]     = wv0;
    *(ushort8*)&Ws[srow][scol + 8] = wv1;
    __syncthreads();

    short8 af[4], wf[4];
    #pragma unroll
    for (int m = 0; m < 4; m++) af[m] = *(const short8*)&As[wr + m * 16 + l15][lhi * 8];
    #pragma unroll
    for (int n = 0; n < 4; n++) wf[n] = *(const short8*)&Ws[wc + n * 16 + l15][lhi * 8];
    #pragma unroll
    for (int m = 0; m < 4; m++)
      #pragma unroll
      for (int n = 0; n < 4; n++)
        acc[m][n] = __builtin_amdgcn_mfma_f32_16x16x32_bf16(af[m], wf[n], acc[m][n], 0, 0, 0);
    __syncthreads();
  }

  #pragma unroll
  for (int n = 0; n < 4; n++) {
    int col = cn + wc + n * 16 + l15;
    float bv = HAS_BIAS ? bias[col] : 0.0f;
    #pragma unroll
    for (int m = 0; m < 4; m++) {
      #pragma unroll
      for (int r = 0; r < 4; r++) {
        int row = cm + wr + m * 16 + lhi * 4 + r;
        float v = acc[m][n][r] + bv;
        if (OUT_BF16)
          ((unsigned short*)Cout)[(size_t)row * Nn + col] = f2bf(v);
        else
          ((float*)Cout)[(size_t)row * Nn + col] = v;
      }
    }
  }
}

// ---------------- LayerNorm over 768, rows=2048 ----------------
__global__ __launch_bounds__(256) void k_ln(const float* __restrict__ xin,
    const float* __restrict__ g, const float* __restrict__ b, float* __restrict__ out) {
  int row = blockIdx.x;
  int t = threadIdx.x;
  const float* p = xin + (size_t)row * 768;
  float v0 = p[t], v1 = p[t + 256], v2 = p[t + 512];
  float s = v0 + v1 + v2;
  float s2 = v0 * v0 + v1 * v1 + v2 * v2;
  #pragma unroll
  for (int off = 1; off < 64; off <<= 1) {
    s += __shfl_xor(s, off);
    s2 += __shfl_xor(s2, off);
  }
  __shared__ float ss[4], ss2[4];
  int w = t >> 6;
  if ((t & 63) == 0) { ss[w] = s; ss2[w] = s2; }
  __syncthreads();
  s = ss[0] + ss[1] + ss[2] + ss[3];
  s2 = ss2[0] + ss2[1] + ss2[2] + ss2[3];
  float mu = s * (1.0f / 768.0f);
  float var = s2 * (1.0f / 768.0f) - mu * mu;
  float rstd = rsqrtf(var + 1e-5f);
  float* o = out + (size_t)row * 768;
  o[t]       = (v0 - mu) * rstd * g[t]       + b[t];
  o[t + 256] = (v1 - mu) * rstd * g[t + 256] + b[t + 256];
  o[t + 512] = (v2 - mu) * rstd * g[t + 512] + b[t + 512];
}

// ---------------- RoPE on q, repack to [b][h][n][64] bf16 ----------------
__global__ void k_ropeq(const float* __restrict__ q, const float* __restrict__ qtab,
                        unsigned short* __restrict__ qr) {
  int idx = blockIdx.x * 256 + threadIdx.x;
  if (idx >= 2 * 4096 * 12 * 32) return;
  int i = idx & 31;
  int h = (idx >> 5) % 12;
  int bn = idx / 384;               // b*4096 + n
  int n = bn & 4095, b = bn >> 12;
  float2 cs = *(const float2*)(qtab + (n * 32 + i) * 2);
  float2 q2 = *(const float2*)(q + (size_t)bn * 768 + h * 64 + 2 * i);
  float o0 = q2.x * cs.x - q2.y * cs.y;
  float o1 = q2.x * cs.y + q2.y * cs.x;
  unsigned short* dst = qr + ((size_t)(b * 12 + h) * 4096 + n) * 64 + 2 * i;
  dst[0] = f2bf(o0);
  dst[1] = f2bf(o1);
}

// ---------------- split kv, RoPE on k, pack both to [b][h][m][64] bf16 ----------------
__global__ void k_kvpack(const float* __restrict__ kv, const float* __restrict__ ktab,
                         unsigned short* __restrict__ kr, unsigned short* __restrict__ vr) {
  int idx = blockIdx.x * 256 + threadIdx.x;
  if (idx >= 2 * 1024 * 12 * 32) return;
  int i = idx & 31;
  int h = (idx >> 5) % 12;
  int bm = idx / 384;               // b*1024 + m
  int m = bm & 1023, b = bm >> 10;
  const float* rowp = kv + (size_t)bm * 1536;
  float2 k2 = *(const float2*)(rowp + h * 64 + 2 * i);
  float2 v2 = *(const float2*)(rowp + 768 + h * 64 + 2 * i);
  float2 cs = *(const float2*)(ktab + (m * 32 + i) * 2);
  float k0 = k2.x * cs.x - k2.y * cs.y;
  float k1 = k2.x * cs.y + k2.y * cs.x;
  size_t base = ((size_t)(b * 12 + h) * 1024 + m) * 64 + 2 * i;
  kr[base] = f2bf(k0);
  kr[base + 1] = f2bf(k1);
  vr[base] = f2bf(v2.x);
  vr[base + 1] = f2bf(v2.y);
}

// ---------------- masked attention: per (b,h,64-query tile) ----------------
// vis[n] <= 94 keys always; fixed 96-key block, full S in regs (static),
// register softmax, P via LDS transpose, PV MFMA.
__global__ __launch_bounds__(256) void k_attn(
    const unsigned short* __restrict__ qr,   // [b*12][4096][64]
    const unsigned short* __restrict__ kr,   // [b*12][1024][64]
    const unsigned short* __restrict__ vr,   // [b*12][1024][64]
    float* __restrict__ aout)                // [b][4096][768]
{
  __shared__ __align__(16) unsigned short kt_s[96][72];     // keys x dims (+8 pad)
  __shared__ __align__(16) unsigned short vt_s[64][104];    // dims x keys (+8 pad)
  __shared__ __align__(16) unsigned short p_s[4][16][104];  // per-wave P: qrow x key

  const int qt = blockIdx.x;
  const int h = blockIdx.y;
  const int b = blockIdx.z;
  const int bh = b * 12 + h;
  const int tid = threadIdx.x, lane = tid & 63, w = tid >> 6;
  const int l15 = lane & 15, lhi = lane >> 4;

  const unsigned short* kg = kr + (size_t)bh * 1024 * 64;
  #pragma unroll
  for (int it = 0; it < 3; it++) {
    int ch = it * 256 + tid;                   // 768 = 96 rows * 8 chunks
    int row = ch >> 3, c8 = (ch & 7) * 8;
    *(ushort8*)&kt_s[row][c8] = *(const ushort8*)(kg + row * 64 + c8);
  }
  const unsigned short* vg = vr + (size_t)bh * 1024 * 64;
  #pragma unroll
  for (int it = 0; it < 24; it++) {
    int e = it * 256 + tid;                    // 6144 = 96 rows * 64 dims
    int row = e >> 6, d = e & 63;
    vt_s[d][row] = vg[row * 64 + d];
  }
  __syncthreads();

  // Q fragments straight from global (A-operand layout)
  const unsigned short* qg = qr + (size_t)bh * 4096 * 64
                           + (size_t)(qt * 64 + w * 16 + l15) * 64 + lhi * 8;
  short8 qf0 = *(const short8*)qg;
  short8 qf1 = *(const short8*)(qg + 32);

  f32x4 zero = {0.f, 0.f, 0.f, 0.f};
  f32x4 sacc[6];
  #pragma unroll
  for (int g = 0; g < 6; g++) sacc[g] = zero;
  #pragma unroll
  for (int g = 0; g < 6; g++) {
    short8 kf0 = *(const short8*)&kt_s[g * 16 + l15][lhi * 8];
    short8 kf1 = *(const short8*)&kt_s[g * 16 + l15][32 + lhi * 8];
    sacc[g] = __builtin_amdgcn_mfma_f32_16x16x32_bf16(qf0, kf0, sacc[g], 0, 0, 0);
    sacc[g] = __builtin_amdgcn_mfma_f32_16x16x32_bf16(qf1, kf1, sacc[g], 0, 0, 0);
  }

  int visv[4];
  #pragma unroll
  for (int r = 0; r < 4; r++) {
    int n = qt * 64 + w * 16 + lhi * 4 + r;
    visv[r] = 2 * (n >> 7) + (((n >> 6) + ((n & 63) << 6)) >> 7) + 1;
  }

  float mx[4] = {-INFINITY, -INFINITY, -INFINITY, -INFINITY};
  #pragma unroll
  for (int g = 0; g < 6; g++) {
    int key = g * 16 + l15;
    #pragma unroll
    for (int r = 0; r < 4; r++) {
      float s = (key < visv[r]) ? sacc[g][r] * 0.125f : -INFINITY;
      sacc[g][r] = s;
      mx[r] = fmaxf(mx[r], s);
    }
  }
  #pragma unroll
  for (int off = 1; off < 16; off <<= 1) {
    #pragma unroll
    for (int r = 0; r < 4; r++) mx[r] = fmaxf(mx[r], __shfl_xor(mx[r], off));
  }
  float sum[4] = {0.f, 0.f, 0.f, 0.f};
  #pragma unroll
  for (int g = 0; g < 6; g++) {
    #pragma unroll
    for (int r = 0; r < 4; r++) {
      float pv = __expf(sacc[g][r] - mx[r]);   // masked -> exp(-inf) = 0
      sum[r] += pv;
      p_s[w][lhi * 4 + r][g * 16 + l15] = f2bf(pv);
    }
  }
  #pragma unroll
  for (int off = 1; off < 16; off <<= 1) {
    #pragma unroll
    for (int r = 0; r < 4; r++) sum[r] += __shfl_xor(sum[r], off);
  }
  __syncthreads();

  f32x4 oacc[4];
  #pragma unroll
  for (int dg = 0; dg < 4; dg++) oacc[dg] = zero;
  #pragma unroll
  for (int ks = 0; ks < 3; ks++) {
    short8 pa = *(const short8*)&p_s[w][l15][ks * 32 + lhi * 8];
    #pragma unroll
    for (int dg = 0; dg < 4; dg++) {
      short8 vb = *(const short8*)&vt_s[dg * 16 + l15][ks * 32 + lhi * 8];
      oacc[dg] = __builtin_amdgcn_mfma_f32_16x16x32_bf16(pa, vb, oacc[dg], 0, 0, 0);
    }
  }

  float* ob = aout + ((size_t)b * 4096 + qt * 64 + w * 16) * 768 + h * 64;
  #pragma unroll
  for (int dg = 0; dg < 4; dg++) {
    int d = dg * 16 + l15;
    #pragma unroll
    for (int r = 0; r < 4; r++) {
      ob[(size_t)(lhi * 4 + r) * 768 + d] = oacc[dg][r] / sum[r];
    }
  }
}

extern "C" void kernel_launch(void* const* d_in, const int* in_sizes, int n_in,
                              void* d_out, int out_size, void* d_ws, size_t ws_size,
                              hipStream_t stream) {
  const float* x   = (const float*)d_in[0];
  const float* Wq  = (const float*)d_in[1];
  const float* Wkv = (const float*)d_in[2];
  const float* srw = (const float*)d_in[3];
  const float* srb = (const float*)d_in[4];
  const float* lng = (const float*)d_in[5];
  const float* lnb = (const float*)d_in[6];
  const float* pw  = (const float*)d_in[7];
  const float* pb  = (const float*)d_in[8];

  // Workspace layout (52.3 MiB total), liveness-overlapped:
  //   qtab  [0,        1048576)
  //   ktab  [1048576,  1310720)
  //   A     [1310720,  26476544): qf32 -> asr -> kvb -> attnout (sequential lifetimes)
  //   qrope [26476544, 39059456)
  //   W     [39059456, 48496640): wsrp -> xrn -> (krope, vpack)
  //   xrpre [48496640, 54788096)
  char* ws = (char*)d_ws;
  float* qtab           = (float*)(ws);
  float* ktab           = (float*)(ws + 1048576);
  float* bufA           = (float*)(ws + 1310720);             // 25,165,824 B region
  unsigned short* qrope = (unsigned short*)(ws + 26476544);   // 12,582,912 B
  float* wsrp           = (float*)(ws + 39059456);            //  9,437,184 B region
  float* xrn            = (float*)(ws + 39059456);            //  3,145,728 B (after wsrp dead)
  unsigned short* krope = (unsigned short*)(ws + 39059456);   //  3,145,728 B (after xrn dead)
  unsigned short* vpack = (unsigned short*)(ws + 42205184);   //  3,145,728 B
  float* xrpre          = (float*)(ws + 48496640);            //  6,291,456 B

  k_tables<<<640, 256, 0, stream>>>(qtab, ktab);
  // q = x @ Wq^T (f32 out in A), then RoPE+repack to bf16 [b][h][n][64]
  k_gemm<false, false><<<dim3(6, 64), 256, 0, stream>>>(x, Wq, nullptr, bufA, 8192, 768, 768);
  k_ropeq<<<12288, 256, 0, stream>>>(bufA, qtab, qrope);
  // conv-as-GEMM: gather (A region) + weight repack (W region)
  k_gather<<<6144, 256, 0, stream>>>(x, bufA);
  k_repack<<<9216, 256, 0, stream>>>(srw, wsrp);
  k_gemm<true, false><<<dim3(6, 16), 256, 0, stream>>>(bufA, wsrp, srb, xrpre, 2048, 768, 3072);
  k_ln<<<2048, 256, 0, stream>>>(xrpre, lng, lnb, xrn);
  // kv = xr @ Wkv^T (into A region), split + RoPE(k) + pack (into W region)
  k_gemm<false, false><<<dim3(12, 16), 256, 0, stream>>>(xrn, Wkv, nullptr, bufA, 2048, 1536, 768);
  k_kvpack<<<3072, 256, 0, stream>>>(bufA, ktab, krope, vpack);
  // masked attention -> attn_out f32 (A region)
  k_attn<<<dim3(64, 12, 2), 256, 0, stream>>>(qrope, krope, vpack, bufA);
  // out = attn_out @ proj_w^T + proj_b, f32 epilogue into d_out (output dtype = float32!)
  k_gemm<true, false><<<dim3(6, 64), 256, 0, stream>>>(bufA, pw, pb, d_out, 8192, 768, 768);
}

// Round 4
// 147.735 us; speedup vs baseline: 1.9358x; 1.9358x over previous
//
#include <hip/hip_runtime.h>
#include <hip/hip_bf16.h>
#include <math.h>

typedef __attribute__((ext_vector_type(4))) float f32x4;
typedef __attribute__((ext_vector_type(8))) short short8;
typedef __attribute__((ext_vector_type(8))) unsigned short ushort8;
typedef __attribute__((ext_vector_type(4))) unsigned short ushort4v;

__device__ __forceinline__ unsigned short f2bf(float f) {
  __hip_bfloat16 h = __float2bfloat16(f);
  return *reinterpret_cast<unsigned short*>(&h);
}
__device__ __forceinline__ float bf2f(unsigned short u) {
  unsigned v = ((unsigned)u) << 16;
  return *reinterpret_cast<float*>(&v);
}

// ---------------- RoPE angle tables (cos,sin interleaved) ----------------
__global__ void k_tables(float* __restrict__ qtab, float* __restrict__ ktab) {
  int idx = blockIdx.x * 256 + threadIdx.x;
  if (idx < 4096 * 32) {
    int n = idx >> 5, i = idx & 31;
    float freq = powf(10000.0f, -(float)(i >> 1) * (1.0f / 16.0f));
    float pos = (i & 1) ? (float)(n >> 6) : (float)(n & 63);
    float a = pos * freq;
    qtab[idx * 2] = cosf(a);
    qtab[idx * 2 + 1] = sinf(a);
  } else if (idx < 4096 * 32 + 1024 * 32) {
    int t = idx - 4096 * 32;
    int m = t >> 5, i = t & 31;
    float freq = powf(10000.0f, -(float)(i >> 1) * (1.0f / 16.0f));
    float pos = (i & 1) ? (0.5f + 2.0f * (float)(m >> 6)) : (0.5f + 2.0f * (float)(m & 63));
    float a = pos * freq;
    ktab[t * 2] = cosf(a);
    ktab[t * 2 + 1] = sinf(a);
  }
}

// ---------------- f32 -> bf16 convert, 4 elems/thread ----------------
__global__ void k_cvt(const float* __restrict__ s, unsigned short* __restrict__ d, int n) {
  int idx = (blockIdx.x * 256 + threadIdx.x) * 4;
  if (idx >= n) return;
  float4 v = *(const float4*)(s + idx);
  ushort4v o;
  o[0] = f2bf(v.x); o[1] = f2bf(v.y); o[2] = f2bf(v.z); o[3] = f2bf(v.w);
  *(ushort4v*)(d + idx) = o;
}

// ---------------- sr_w (O,C,2,2) -> bf16 [patch][O][C] ----------------
__global__ void k_srw(const float* __restrict__ srw, unsigned short* __restrict__ wp) {
  int g = blockIdx.x * 256 + threadIdx.x;
  if (g >= 4 * 768 * 768) return;
  int patch = g / 589824;
  int rem = g - patch * 589824;
  int o = rem / 768;
  int c = rem - o * 768;
  wp[g] = f2bf(srw[o * 3072 + c * 4 + patch]);
}

// ---------------- pipelined bf16 GEMM: C = A @ W^T ----------------
// 128x128 tile, BK=32, 4 waves (2x2), 2-deep reg prefetch, double-buffered LDS.
// EPI: 0 = f32+bias -> O0 (proj)
//      1 = bf16 partial -> O0 + patch*M*N (conv split-K)
//      2 = RoPE-Q -> qrope [b*12+h][4096][64] bf16
//      3 = RoPE-K -> kr, V -> vr  [b*12+h][1024][64] bf16
template<int EPI, bool REMAP>
__global__ __launch_bounds__(256) void k_gemm(
    const unsigned short* __restrict__ A, const unsigned short* __restrict__ W,
    void* __restrict__ O0, void* __restrict__ O1,
    const float* __restrict__ bias, const float* __restrict__ tab,
    int M, int Nn, int K)
{
  __shared__ __align__(16) unsigned short As[2][128][40];  // 80B rows (16B mult)
  __shared__ __align__(16) unsigned short Ws[2][128][40];
  const int tid = threadIdx.x, lane = tid & 63, wid = tid >> 6;
  const int wr = (wid >> 1) * 64, wc = (wid & 1) * 64;
  const int l15 = lane & 15, lhi = lane >> 4;
  const int cm = blockIdx.y * 128, cn = blockIdx.x * 128;
  const int patch = REMAP ? blockIdx.z : 0;

  const int srow = tid >> 1, shalf = tid & 1;

  const unsigned short* ap;
  if (REMAP) {
    // conv-as-GEMM: A row rt maps to a gathered row of x
    int rt = cm + srow;
    int bb = rt >> 10, p = rt & 1023, oh = p >> 5, ow = p & 31;
    int kh = patch >> 1, kw = patch & 1;
    int src = bb * 4096 + (2 * oh + kh) * 64 + 2 * ow + kw;
    ap = A + (size_t)src * K + shalf * 16;
  } else {
    ap = A + (size_t)(cm + srow) * K + shalf * 16;
  }
  const unsigned short* wpp = W + (REMAP ? (size_t)patch * Nn * K : 0)
                            + (size_t)(cn + srow) * K + shalf * 16;

  f32x4 zero = {0.f, 0.f, 0.f, 0.f};
  f32x4 acc[4][4];
  #pragma unroll
  for (int i = 0; i < 4; i++)
    #pragma unroll
    for (int j = 0; j < 4; j++) acc[i][j] = zero;

  const int NT = K >> 5;
  ushort8 ra0, ra1, rw0, rw1;
#define LOADT(kt) { int kk = (kt) * 32; \
    ra0 = *(const ushort8*)(ap + kk);  ra1 = *(const ushort8*)(ap + kk + 8); \
    rw0 = *(const ushort8*)(wpp + kk); rw1 = *(const ushort8*)(wpp + kk + 8); }
#define STORET(bi) { \
    *(ushort8*)&As[bi][srow][shalf * 16]     = ra0; \
    *(ushort8*)&As[bi][srow][shalf * 16 + 8] = ra1; \
    *(ushort8*)&Ws[bi][srow][shalf * 16]     = rw0; \
    *(ushort8*)&Ws[bi][srow][shalf * 16 + 8] = rw1; }

  LOADT(0);
  STORET(0);
  LOADT(1);
  __syncthreads();

  for (int kt = 0; kt < NT; ++kt) {
    const int bi = kt & 1;
    short8 af[4], wf[4];
    #pragma unroll
    for (int m = 0; m < 4; m++) af[m] = *(const short8*)&As[bi][wr + m * 16 + l15][lhi * 8];
    #pragma unroll
    for (int n = 0; n < 4; n++) wf[n] = *(const short8*)&Ws[bi][wc + n * 16 + l15][lhi * 8];
    #pragma unroll
    for (int m = 0; m < 4; m++)
      #pragma unroll
      for (int n = 0; n < 4; n++)
        acc[m][n] = __builtin_amdgcn_mfma_f32_16x16x32_bf16(af[m], wf[n], acc[m][n], 0, 0, 0);
    if (kt + 1 < NT) {
      STORET(bi ^ 1);                 // compiler inserts vmcnt wait on ra*/rw*
      if (kt + 2 < NT) LOADT(kt + 2); // 2-deep prefetch
    }
    __syncthreads();
  }
#undef LOADT
#undef STORET

  if (EPI == 0) {
    float* O = (float*)O0;
    #pragma unroll
    for (int n = 0; n < 4; n++) {
      int col = cn + wc + n * 16 + l15;
      float bv = bias[col];
      #pragma unroll
      for (int m = 0; m < 4; m++)
        #pragma unroll
        for (int r = 0; r < 4; r++) {
          int row = cm + wr + m * 16 + lhi * 4 + r;
          O[(size_t)row * Nn + col] = acc[m][n][r] + bv;
        }
    }
  } else if (EPI == 1) {
    unsigned short* O = (unsigned short*)O0 + (size_t)patch * M * Nn;
    #pragma unroll
    for (int n = 0; n < 4; n++) {
      int col = cn + wc + n * 16 + l15;
      #pragma unroll
      for (int m = 0; m < 4; m++)
        #pragma unroll
        for (int r = 0; r < 4; r++) {
          int row = cm + wr + m * 16 + lhi * 4 + r;
          O[(size_t)row * Nn + col] = f2bf(acc[m][n][r]);
        }
    }
  } else if (EPI == 2) {
    // RoPE-Q: pair element lives in lane l15^1 (adjacent column)
    unsigned short* qr = (unsigned short*)O0;
    const float2* t2 = (const float2*)tab;
    #pragma unroll
    for (int n = 0; n < 4; n++) {
      int col = cn + wc + n * 16 + l15;
      int hh = col >> 6, d = col & 63, i = d >> 1;
      #pragma unroll
      for (int m = 0; m < 4; m++)
        #pragma unroll
        for (int r = 0; r < 4; r++) {
          int row = cm + wr + m * 16 + lhi * 4 + r;
          int bb = row >> 12, np = row & 4095;
          float v = acc[m][n][r];
          float p = __shfl_xor(v, 1);
          float2 cs = t2[np * 32 + i];
          float o = (d & 1) ? (p * cs.y + v * cs.x) : (v * cs.x - p * cs.y);
          qr[((size_t)(bb * 12 + hh) * 4096 + np) * 64 + d] = f2bf(o);
        }
    }
  } else {
    // KV: cols 0..767 -> K (RoPE), 768..1535 -> V (plain)
    unsigned short* kr = (unsigned short*)O0;
    unsigned short* vr = (unsigned short*)O1;
    const float2* t2 = (const float2*)tab;
    #pragma unroll
    for (int n = 0; n < 4; n++) {
      int col = cn + wc + n * 16 + l15;
      bool isk = (col < 768);
      int c2 = isk ? col : col - 768;
      int hh = c2 >> 6, d = c2 & 63, i = d >> 1;
      #pragma unroll
      for (int m = 0; m < 4; m++)
        #pragma unroll
        for (int r = 0; r < 4; r++) {
          int row = cm + wr + m * 16 + lhi * 4 + r;
          int bb = row >> 10, mm = row & 1023;
          float v = acc[m][n][r];
          float p = __shfl_xor(v, 1);   // all lanes execute (shfl outside divergence)
          size_t o = ((size_t)(bb * 12 + hh) * 1024 + mm) * 64 + d;
          if (isk) {
            float2 cs = t2[mm * 32 + i];
            float ov = (d & 1) ? (p * cs.y + v * cs.x) : (v * cs.x - p * cs.y);
            kr[o] = f2bf(ov);
          } else {
            vr[o] = f2bf(v);
          }
        }
    }
  }
}

// ---------------- fused partial-reduce + bias + LayerNorm -> bf16 ----------------
__global__ __launch_bounds__(256) void k_lnr(const unsigned short* __restrict__ part,
    const float* __restrict__ srb, const float* __restrict__ g,
    const float* __restrict__ b, unsigned short* __restrict__ out) {
  int row = blockIdx.x;
  int t = threadIdx.x;
  float v[3];
  #pragma unroll
  for (int j = 0; j < 3; j++) {
    int c = t + j * 256;
    float s = srb[c];
    #pragma unroll
    for (int p = 0; p < 4; p++)
      s += bf2f(part[((size_t)p * 2048 + row) * 768 + c]);
    v[j] = s;
  }
  float s = v[0] + v[1] + v[2];
  float s2 = v[0] * v[0] + v[1] * v[1] + v[2] * v[2];
  #pragma unroll
  for (int off = 1; off < 64; off <<= 1) {
    s += __shfl_xor(s, off);
    s2 += __shfl_xor(s2, off);
  }
  __shared__ float ss[4], ss2[4];
  int w = t >> 6;
  if ((t & 63) == 0) { ss[w] = s; ss2[w] = s2; }
  __syncthreads();
  s = ss[0] + ss[1] + ss[2] + ss[3];
  s2 = ss2[0] + ss2[1] + ss2[2] + ss2[3];
  float mu = s * (1.0f / 768.0f);
  float var = s2 * (1.0f / 768.0f) - mu * mu;
  float rstd = rsqrtf(var + 1e-5f);
  unsigned short* o = out + (size_t)row * 768;
  #pragma unroll
  for (int j = 0; j < 3; j++) {
    int c = t + j * 256;
    o[c] = f2bf((v[j] - mu) * rstd * g[c] + b[c]);
  }
}

// ---------------- masked attention: per (b,h,64-query tile), bf16 out ----------------
__global__ __launch_bounds__(256) void k_attn(
    const unsigned short* __restrict__ qr,   // [b*12][4096][64]
    const unsigned short* __restrict__ kr,   // [b*12][1024][64]
    const unsigned short* __restrict__ vr,   // [b*12][1024][64]
    unsigned short* __restrict__ aout)       // [b][4096][768] bf16
{
  __shared__ __align__(16) unsigned short kt_s[96][72];
  __shared__ __align__(16) unsigned short vt_s[64][104];
  __shared__ __align__(16) unsigned short p_s[4][16][104];

  const int qt = blockIdx.x;
  const int h = blockIdx.y;
  const int b = blockIdx.z;
  const int bh = b * 12 + h;
  const int tid = threadIdx.x, lane = tid & 63, w = tid >> 6;
  const int l15 = lane & 15, lhi = lane >> 4;

  const unsigned short* kg = kr + (size_t)bh * 1024 * 64;
  #pragma unroll
  for (int it = 0; it < 3; it++) {
    int ch = it * 256 + tid;
    int row = ch >> 3, c8 = (ch & 7) * 8;
    *(ushort8*)&kt_s[row][c8] = *(const ushort8*)(kg + row * 64 + c8);
  }
  const unsigned short* vg = vr + (size_t)bh * 1024 * 64;
  #pragma unroll
  for (int it = 0; it < 24; it++) {
    int e = it * 256 + tid;
    int row = e >> 6, d = e & 63;
    vt_s[d][row] = vg[row * 64 + d];
  }
  __syncthreads();

  const unsigned short* qg = qr + (size_t)bh * 4096 * 64
                           + (size_t)(qt * 64 + w * 16 + l15) * 64 + lhi * 8;
  short8 qf0 = *(const short8*)qg;
  short8 qf1 = *(const short8*)(qg + 32);

  f32x4 zero = {0.f, 0.f, 0.f, 0.f};
  f32x4 sacc[6];
  #pragma unroll
  for (int g = 0; g < 6; g++) sacc[g] = zero;
  #pragma unroll
  for (int g = 0; g < 6; g++) {
    short8 kf0 = *(const short8*)&kt_s[g * 16 + l15][lhi * 8];
    short8 kf1 = *(const short8*)&kt_s[g * 16 + l15][32 + lhi * 8];
    sacc[g] = __builtin_amdgcn_mfma_f32_16x16x32_bf16(qf0, kf0, sacc[g], 0, 0, 0);
    sacc[g] = __builtin_amdgcn_mfma_f32_16x16x32_bf16(qf1, kf1, sacc[g], 0, 0, 0);
  }

  int visv[4];
  #pragma unroll
  for (int r = 0; r < 4; r++) {
    int n = qt * 64 + w * 16 + lhi * 4 + r;
    visv[r] = 2 * (n >> 7) + (((n >> 6) + ((n & 63) << 6)) >> 7) + 1;
  }

  float mx[4] = {-INFINITY, -INFINITY, -INFINITY, -INFINITY};
  #pragma unroll
  for (int g = 0; g < 6; g++) {
    int key = g * 16 + l15;
    #pragma unroll
    for (int r = 0; r < 4; r++) {
      float s = (key < visv[r]) ? sacc[g][r] * 0.125f : -INFINITY;
      sacc[g][r] = s;
      mx[r] = fmaxf(mx[r], s);
    }
  }
  #pragma unroll
  for (int off = 1; off < 16; off <<= 1) {
    #pragma unroll
    for (int r = 0; r < 4; r++) mx[r] = fmaxf(mx[r], __shfl_xor(mx[r], off));
  }
  float sum[4] = {0.f, 0.f, 0.f, 0.f};
  #pragma unroll
  for (int g = 0; g < 6; g++) {
    #pragma unroll
    for (int r = 0; r < 4; r++) {
      float pv = __expf(sacc[g][r] - mx[r]);
      sum[r] += pv;
      p_s[w][lhi * 4 + r][g * 16 + l15] = f2bf(pv);
    }
  }
  #pragma unroll
  for (int off = 1; off < 16; off <<= 1) {
    #pragma unroll
    for (int r = 0; r < 4; r++) sum[r] += __shfl_xor(sum[r], off);
  }
  __syncthreads();

  f32x4 oacc[4];
  #pragma unroll
  for (int dg = 0; dg < 4; dg++) oacc[dg] = zero;
  #pragma unroll
  for (int ks = 0; ks < 3; ks++) {
    short8 pa = *(const short8*)&p_s[w][l15][ks * 32 + lhi * 8];
    #pragma unroll
    for (int dg = 0; dg < 4; dg++) {
      short8 vb = *(const short8*)&vt_s[dg * 16 + l15][ks * 32 + lhi * 8];
      oacc[dg] = __builtin_amdgcn_mfma_f32_16x16x32_bf16(pa, vb, oacc[dg], 0, 0, 0);
    }
  }

  unsigned short* ob = aout + ((size_t)b * 4096 + qt * 64 + w * 16) * 768 + h * 64;
  #pragma unroll
  for (int dg = 0; dg < 4; dg++) {
    int d = dg * 16 + l15;
    #pragma unroll
    for (int r = 0; r < 4; r++) {
      ob[(size_t)(lhi * 4 + r) * 768 + d] = f2bf(oacc[dg][r] / sum[r]);
    }
  }
}

extern "C" void kernel_launch(void* const* d_in, const int* in_sizes, int n_in,
                              void* d_out, int out_size, void* d_ws, size_t ws_size,
                              hipStream_t stream) {
  const float* x   = (const float*)d_in[0];
  const float* Wq  = (const float*)d_in[1];
  const float* Wkv = (const float*)d_in[2];
  const float* srw = (const float*)d_in[3];
  const float* srb = (const float*)d_in[4];
  const float* lng = (const float*)d_in[5];
  const float* lnb = (const float*)d_in[6];
  const float* pw  = (const float*)d_in[7];
  const float* pb  = (const float*)d_in[8];

  // Workspace (49.3 MiB peak), liveness-overlapped:
  //  qtab   [0,         1048576)
  //  ktab   [1048576,   1310720)
  //  xb     [1310720,  13893632)  bf16 x; reused as attn_out after conv GEMM
  //  qrope  [13893632, 26476544)
  //  partial[26476544, 39059456)  bf16 [4][2048][768]; after lnr: kr, vr overlay
  //  wqb    [39059456, 40239104)
  //  wkvb   [40239104, 42598400)
  //  pwb    [42598400, 43778048)
  //  wsrb   [43778048, 48496640)  bf16 [4][768][768]
  //  xrn    [48496640, 51642368)  bf16 [2048][768]
  char* ws = (char*)d_ws;
  float* qtab           = (float*)(ws);
  float* ktab           = (float*)(ws + 1048576);
  unsigned short* xb    = (unsigned short*)(ws + 1310720);
  unsigned short* attno = xb;  // reuse after xb dead
  unsigned short* qrope = (unsigned short*)(ws + 13893632);
  unsigned short* part  = (unsigned short*)(ws + 26476544);
  unsigned short* kr    = (unsigned short*)(ws + 26476544);   // overlays part (dead)
  unsigned short* vr    = (unsigned short*)(ws + 29622272);
  unsigned short* wqb   = (unsigned short*)(ws + 39059456);
  unsigned short* wkvb  = (unsigned short*)(ws + 40239104);
  unsigned short* pwb   = (unsigned short*)(ws + 42598400);
  unsigned short* wsrb  = (unsigned short*)(ws + 43778048);
  unsigned short* xrn   = (unsigned short*)(ws + 48496640);

  k_tables<<<640, 256, 0, stream>>>(qtab, ktab);
  k_cvt<<<6144, 256, 0, stream>>>(x, xb, 6291456);
  k_cvt<<<576, 256, 0, stream>>>(Wq, wqb, 589824);
  k_cvt<<<1152, 256, 0, stream>>>(Wkv, wkvb, 1179648);
  k_cvt<<<576, 256, 0, stream>>>(pw, pwb, 589824);
  k_srw<<<9216, 256, 0, stream>>>(srw, wsrb);

  // Q = x @ Wq^T, RoPE fused in epilogue -> qrope bf16
  k_gemm<2, false><<<dim3(6, 64), 256, 0, stream>>>(xb, wqb, qrope, nullptr, nullptr, qtab, 8192, 768, 768);
  // conv split-K over 4 patches (row-gathered x, no A materialization) -> bf16 partials
  k_gemm<1, true><<<dim3(6, 16, 4), 256, 0, stream>>>(xb, wsrb, part, nullptr, nullptr, nullptr, 2048, 768, 768);
  // reduce partials + sr_b + LayerNorm -> xrn bf16
  k_lnr<<<2048, 256, 0, stream>>>(part, srb, lng, lnb, xrn);
  // KV = xrn @ Wkv^T, RoPE-K + V pack fused -> kr, vr bf16
  k_gemm<3, false><<<dim3(12, 16), 256, 0, stream>>>(xrn, wkvb, kr, vr, nullptr, ktab, 2048, 1536, 768);
  // masked attention -> attn_out bf16 (xb region)
  k_attn<<<dim3(64, 12, 2), 256, 0, stream>>>(qrope, kr, vr, attno);
  // out = attn_out @ proj_w^T + proj_b -> f32 d_out
  k_gemm<0, false><<<dim3(6, 64), 256, 0, stream>>>(attno, pwb, d_out, nullptr, pb, nullptr, 8192, 768, 768);
}

// Round 5
// 134.012 us; speedup vs baseline: 2.1340x; 1.1024x over previous
//
#include <hip/hip_runtime.h>
#include <hip/hip_bf16.h>
#include <math.h>

typedef __attribute__((ext_vector_type(4))) float f32x4;
typedef __attribute__((ext_vector_type(8))) short short8;
typedef __attribute__((ext_vector_type(8))) unsigned short ushort8;
typedef __attribute__((ext_vector_type(4))) unsigned short ushort4v;

__device__ __forceinline__ unsigned short f2bf(float f) {
  __hip_bfloat16 h = __float2bfloat16(f);
  return *reinterpret_cast<unsigned short*>(&h);
}
__device__ __forceinline__ float bf2f(unsigned short u) {
  unsigned v = ((unsigned)u) << 16;
  return *reinterpret_cast<float*>(&v);
}
// async global->LDS, 16B per lane; LDS dest must be wave-uniform base (HW adds lane*16)
__device__ __forceinline__ void async16(const void* g, void* l) {
  __builtin_amdgcn_global_load_lds(
      (__attribute__((address_space(1))) void*)g,
      (__attribute__((address_space(3))) void*)l, 16, 0, 0);
}

// ---------------- fused prep: RoPE tables + all f32->bf16 casts + sr_w repack ----------------
__global__ __launch_bounds__(256) void k_prep(
    const float* __restrict__ x, const float* __restrict__ Wq,
    const float* __restrict__ Wkv, const float* __restrict__ pw,
    const float* __restrict__ srw,
    float* __restrict__ qtab, float* __restrict__ ktab,
    unsigned short* __restrict__ xb, unsigned short* __restrict__ wqb,
    unsigned short* __restrict__ wkvb, unsigned short* __restrict__ pwb,
    unsigned short* __restrict__ wsrb)
{
  int idx = blockIdx.x * 256 + threadIdx.x;
  if (idx < 131072) {                       // q-table [4096][32]
    int n = idx >> 5, i = idx & 31;
    float freq = powf(10000.0f, -(float)(i >> 1) * (1.0f / 16.0f));
    float pos = (i & 1) ? (float)(n >> 6) : (float)(n & 63);
    float a = pos * freq;
    qtab[idx * 2] = cosf(a);
    qtab[idx * 2 + 1] = sinf(a);
  } else if (idx < 163840) {                // k-table [1024][32]
    int t = idx - 131072;
    int m = t >> 5, i = t & 31;
    float freq = powf(10000.0f, -(float)(i >> 1) * (1.0f / 16.0f));
    float pos = (i & 1) ? (0.5f + 2.0f * (float)(m >> 6)) : (0.5f + 2.0f * (float)(m & 63));
    float a = pos * freq;
    ktab[t * 2] = cosf(a);
    ktab[t * 2 + 1] = sinf(a);
  } else if (idx < 1736704) {               // x cvt (float4 units)
    int g = idx - 163840;
    float4 v = ((const float4*)x)[g];
    ushort4v o; o[0]=f2bf(v.x); o[1]=f2bf(v.y); o[2]=f2bf(v.z); o[3]=f2bf(v.w);
    *(ushort4v*)(xb + g * 4) = o;
  } else if (idx < 1884160) {               // Wq cvt
    int g = idx - 1736704;
    float4 v = ((const float4*)Wq)[g];
    ushort4v o; o[0]=f2bf(v.x); o[1]=f2bf(v.y); o[2]=f2bf(v.z); o[3]=f2bf(v.w);
    *(ushort4v*)(wqb + g * 4) = o;
  } else if (idx < 2179072) {               // Wkv cvt
    int g = idx - 1884160;
    float4 v = ((const float4*)Wkv)[g];
    ushort4v o; o[0]=f2bf(v.x); o[1]=f2bf(v.y); o[2]=f2bf(v.z); o[3]=f2bf(v.w);
    *(ushort4v*)(wkvb + g * 4) = o;
  } else if (idx < 2326528) {               // proj_w cvt
    int g = idx - 2179072;
    float4 v = ((const float4*)pw)[g];
    ushort4v o; o[0]=f2bf(v.x); o[1]=f2bf(v.y); o[2]=f2bf(v.z); o[3]=f2bf(v.w);
    *(ushort4v*)(pwb + g * 4) = o;
  } else if (idx < 4685824) {               // sr_w (O,C,2,2) -> [patch][O][C], source-linear
    int g = idx - 2326528;
    int o = g / 3072;
    int rem = g - o * 3072;
    int c = rem >> 2, patch = rem & 3;
    wsrb[(size_t)patch * 589824 + o * 768 + c] = f2bf(srw[g]);
  }
}

// ---------------- GEMM via global_load_lds, 128x128 tile, BK=32, double-buffered ----------------
// MODE 0: proj  (grid 6x64)  : O0=f32 d_out (+bias)
// MODE 1: kv    (grid 12x16) : O0=kr (RoPE), O1=vr
// MODE 2: qconv (flat 768)   : bid<384 Q->O0=qrope (RoPE); else conv patch->O1=part (bf16)
// K = 768 always, A/W bf16.
template<int MODE>
__global__ __launch_bounds__(256) void k_g(
    const unsigned short* __restrict__ A, const unsigned short* __restrict__ W,
    const unsigned short* __restrict__ W2,
    void* __restrict__ O0, void* __restrict__ O1,
    const float* __restrict__ bias, const float* __restrict__ tab)
{
  __shared__ __align__(16) unsigned short As[2][128][32];
  __shared__ __align__(16) unsigned short Ws[2][128][32];
  const int tid = threadIdx.x, lane = tid & 63, wid = tid >> 6;
  const int wr = (wid >> 1) * 64, wc = (wid & 1) * 64;
  const int l15 = lane & 15, lhi = lane >> 4;
  const int K = 768, NT = 24;
  const int Nn = (MODE == 1) ? 1536 : 768;

  int cm, cn, patch = 0;
  bool isconv = false;
  if (MODE == 2) {
    int bid = blockIdx.x;
    if (bid < 384) { cm = (bid / 6) * 128; cn = (bid % 6) * 128; }
    else {
      int c = bid - 384; isconv = true;
      patch = c / 96; int r = c - patch * 96;
      cm = (r / 6) * 128; cn = (r % 6) * 128;
    }
  } else {
    cm = blockIdx.y * 128; cn = blockIdx.x * 128;
  }

  // staging: wave w covers rows [w*32, w*32+32) of both tiles; 2 calls x 16 rows each.
  // lane l: row = base + (l>>2), 16B chunk = l&3  ==> LDS linear offset l*16 B. 
  size_t aoff0, aoff1;
  {
    int r0 = cm + wid * 32 + (lane >> 2);
    int r1 = r0 + 16;
    if (MODE == 2 && isconv) {
      int kh = patch >> 1, kw = patch & 1;
      int b0 = r0 >> 10, p0 = r0 & 1023;
      int b1 = r1 >> 10, p1 = r1 & 1023;
      r0 = b0 * 4096 + (2 * (p0 >> 5) + kh) * 64 + 2 * (p0 & 31) + kw;
      r1 = b1 * 4096 + (2 * (p1 >> 5) + kh) * 64 + 2 * (p1 & 31) + kw;
    }
    aoff0 = (size_t)r0 * K + (lane & 3) * 8;
    aoff1 = (size_t)r1 * K + (lane & 3) * 8;
  }
  const unsigned short* wbase = (MODE == 2 && isconv) ? (W2 + (size_t)patch * 589824) : W;
  size_t woff0 = (size_t)(cn + wid * 32 + (lane >> 2)) * K + (lane & 3) * 8;
  size_t woff1 = woff0 + (size_t)16 * K;

#define STAGE(bi, kt) { \
    async16(A + aoff0 + (kt) * 32,     &As[bi][wid * 32][0]);      \
    async16(A + aoff1 + (kt) * 32,     &As[bi][wid * 32 + 16][0]); \
    async16(wbase + woff0 + (kt) * 32, &Ws[bi][wid * 32][0]);      \
    async16(wbase + woff1 + (kt) * 32, &Ws[bi][wid * 32 + 16][0]); }

  f32x4 zero = {0.f, 0.f, 0.f, 0.f};
  f32x4 acc[4][4];
  #pragma unroll
  for (int i = 0; i < 4; i++)
    #pragma unroll
    for (int j = 0; j < 4; j++) acc[i][j] = zero;

  STAGE(0, 0);
  __syncthreads();              // drains vmcnt(0): buf0 ready

  #pragma unroll 2
  for (int kt = 0; kt < NT; ++kt) {
    const int bi = kt & 1;
    if (kt + 1 < NT) STAGE(bi ^ 1, kt + 1);   // in flight under compute
    short8 af[4], wf[4];
    #pragma unroll
    for (int m = 0; m < 4; m++) af[m] = *(const short8*)&As[bi][wr + m * 16 + l15][lhi * 8];
    #pragma unroll
    for (int n = 0; n < 4; n++) wf[n] = *(const short8*)&Ws[bi][wc + n * 16 + l15][lhi * 8];
    #pragma unroll
    for (int m = 0; m < 4; m++)
      #pragma unroll
      for (int n = 0; n < 4; n++)
        acc[m][n] = __builtin_amdgcn_mfma_f32_16x16x32_bf16(af[m], wf[n], acc[m][n], 0, 0, 0);
    __syncthreads();            // drains vmcnt+lgkm: next buffer staged, reads done
  }
#undef STAGE

  if (MODE == 0) {
    float* O = (float*)O0;
    #pragma unroll
    for (int n = 0; n < 4; n++) {
      int col = cn + wc + n * 16 + l15;
      float bv = bias[col];
      #pragma unroll
      for (int m = 0; m < 4; m++)
        #pragma unroll
        for (int r = 0; r < 4; r++) {
          int row = cm + wr + m * 16 + lhi * 4 + r;
          O[(size_t)row * Nn + col] = acc[m][n][r] + bv;
        }
    }
  } else if (MODE == 1) {
    // cols 0..767 -> K (RoPE), 768..1535 -> V
    unsigned short* kr = (unsigned short*)O0;
    unsigned short* vr = (unsigned short*)O1;
    const float2* t2 = (const float2*)tab;
    #pragma unroll
    for (int n = 0; n < 4; n++) {
      int col = cn + wc + n * 16 + l15;
      bool isk = (col < 768);
      int c2 = isk ? col : col - 768;
      int hh = c2 >> 6, d = c2 & 63, i = d >> 1;
      #pragma unroll
      for (int m = 0; m < 4; m++)
        #pragma unroll
        for (int r = 0; r < 4; r++) {
          int row = cm + wr + m * 16 + lhi * 4 + r;
          int bb = row >> 10, mm = row & 1023;
          float v = acc[m][n][r];
          float p = __shfl_xor(v, 1);
          size_t o = ((size_t)(bb * 12 + hh) * 1024 + mm) * 64 + d;
          if (isk) {
            float2 cs = t2[mm * 32 + i];
            float ov = (d & 1) ? (p * cs.y + v * cs.x) : (v * cs.x - p * cs.y);
            kr[o] = f2bf(ov);
          } else {
            vr[o] = f2bf(v);
          }
        }
    }
  } else {
    if (!isconv) {
      // RoPE-Q -> qrope [b*12+h][4096][64]
      unsigned short* qr = (unsigned short*)O0;
      const float2* t2 = (const float2*)tab;
      #pragma unroll
      for (int n = 0; n < 4; n++) {
        int col = cn + wc + n * 16 + l15;
        int hh = col >> 6, d = col & 63, i = d >> 1;
        #pragma unroll
        for (int m = 0; m < 4; m++)
          #pragma unroll
          for (int r = 0; r < 4; r++) {
            int row = cm + wr + m * 16 + lhi * 4 + r;
            int bb = row >> 12, np = row & 4095;
            float v = acc[m][n][r];
            float p = __shfl_xor(v, 1);
            float2 cs = t2[np * 32 + i];
            float o = (d & 1) ? (p * cs.y + v * cs.x) : (v * cs.x - p * cs.y);
            qr[((size_t)(bb * 12 + hh) * 4096 + np) * 64 + d] = f2bf(o);
          }
      }
    } else {
      unsigned short* O = (unsigned short*)O1 + (size_t)patch * 2048 * 768;
      #pragma unroll
      for (int n = 0; n < 4; n++) {
        int col = cn + wc + n * 16 + l15;
        #pragma unroll
        for (int m = 0; m < 4; m++)
          #pragma unroll
          for (int r = 0; r < 4; r++) {
            int row = cm + wr + m * 16 + lhi * 4 + r;
            O[(size_t)row * 768 + col] = f2bf(acc[m][n][r]);
          }
      }
    }
  }
}

// ---------------- fused partial-reduce + bias + LayerNorm -> bf16 ----------------
__global__ __launch_bounds__(256) void k_lnr(const unsigned short* __restrict__ part,
    const float* __restrict__ srb, const float* __restrict__ g,
    const float* __restrict__ b, unsigned short* __restrict__ out) {
  int row = blockIdx.x;
  int t = threadIdx.x;
  float v[3];
  #pragma unroll
  for (int j = 0; j < 3; j++) {
    int c = t + j * 256;
    float s = srb[c];
    #pragma unroll
    for (int p = 0; p < 4; p++)
      s += bf2f(part[((size_t)p * 2048 + row) * 768 + c]);
    v[j] = s;
  }
  float s = v[0] + v[1] + v[2];
  float s2 = v[0] * v[0] + v[1] * v[1] + v[2] * v[2];
  #pragma unroll
  for (int off = 1; off < 64; off <<= 1) {
    s += __shfl_xor(s, off);
    s2 += __shfl_xor(s2, off);
  }
  __shared__ float ss[4], ss2[4];
  int w = t >> 6;
  if ((t & 63) == 0) { ss[w] = s; ss2[w] = s2; }
  __syncthreads();
  s = ss[0] + ss[1] + ss[2] + ss[3];
  s2 = ss2[0] + ss2[1] + ss2[2] + ss2[3];
  float mu = s * (1.0f / 768.0f);
  float var = s2 * (1.0f / 768.0f) - mu * mu;
  float rstd = rsqrtf(var + 1e-5f);
  unsigned short* o = out + (size_t)row * 768;
  #pragma unroll
  for (int j = 0; j < 3; j++) {
    int c = t + j * 256;
    o[c] = f2bf((v[j] - mu) * rstd * g[c] + b[c]);
  }
}

// ---------------- masked attention: per (b,h,64-query tile), bf16 out ----------------
__global__ __launch_bounds__(256) void k_attn(
    const unsigned short* __restrict__ qr,   // [b*12][4096][64]
    const unsigned short* __restrict__ kr,   // [b*12][1024][64]
    const unsigned short* __restrict__ vr,   // [b*12][1024][64]
    unsigned short* __restrict__ aout)       // [b][4096][768] bf16
{
  __shared__ __align__(16) unsigned short kt_s[96][72];
  __shared__ __align__(16) unsigned short vt_s[64][104];
  __shared__ __align__(16) unsigned short p_s[4][16][104];

  const int qt = blockIdx.x;
  const int h = blockIdx.y;
  const int b = blockIdx.z;
  const int bh = b * 12 + h;
  const int tid = threadIdx.x, lane = tid & 63, w = tid >> 6;
  const int l15 = lane & 15, lhi = lane >> 4;

  const unsigned short* kg = kr + (size_t)bh * 1024 * 64;
  #pragma unroll
  for (int it = 0; it < 3; it++) {
    int ch = it * 256 + tid;
    int row = ch >> 3, c8 = (ch & 7) * 8;
    *(ushort8*)&kt_s[row][c8] = *(const ushort8*)(kg + row * 64 + c8);
  }
  const unsigned short* vg = vr + (size_t)bh * 1024 * 64;
  #pragma unroll
  for (int it = 0; it < 24; it++) {
    int e = it * 256 + tid;
    int row = e >> 6, d = e & 63;
    vt_s[d][row] = vg[row * 64 + d];
  }
  __syncthreads();

  const unsigned short* qg = qr + (size_t)bh * 4096 * 64
                           + (size_t)(qt * 64 + w * 16 + l15) * 64 + lhi * 8;
  short8 qf0 = *(const short8*)qg;
  short8 qf1 = *(const short8*)(qg + 32);

  f32x4 zero = {0.f, 0.f, 0.f, 0.f};
  f32x4 sacc[6];
  #pragma unroll
  for (int g = 0; g < 6; g++) sacc[g] = zero;
  #pragma unroll
  for (int g = 0; g < 6; g++) {
    short8 kf0 = *(const short8*)&kt_s[g * 16 + l15][lhi * 8];
    short8 kf1 = *(const short8*)&kt_s[g * 16 + l15][32 + lhi * 8];
    sacc[g] = __builtin_amdgcn_mfma_f32_16x16x32_bf16(qf0, kf0, sacc[g], 0, 0, 0);
    sacc[g] = __builtin_amdgcn_mfma_f32_16x16x32_bf16(qf1, kf1, sacc[g], 0, 0, 0);
  }

  int visv[4];
  #pragma unroll
  for (int r = 0; r < 4; r++) {
    int n = qt * 64 + w * 16 + lhi * 4 + r;
    visv[r] = 2 * (n >> 7) + (((n >> 6) + ((n & 63) << 6)) >> 7) + 1;
  }

  float mx[4] = {-INFINITY, -INFINITY, -INFINITY, -INFINITY};
  #pragma unroll
  for (int g = 0; g < 6; g++) {
    int key = g * 16 + l15;
    #pragma unroll
    for (int r = 0; r < 4; r++) {
      float s = (key < visv[r]) ? sacc[g][r] * 0.125f : -INFINITY;
      sacc[g][r] = s;
      mx[r] = fmaxf(mx[r], s);
    }
  }
  #pragma unroll
  for (int off = 1; off < 16; off <<= 1) {
    #pragma unroll
    for (int r = 0; r < 4; r++) mx[r] = fmaxf(mx[r], __shfl_xor(mx[r], off));
  }
  float sum[4] = {0.f, 0.f, 0.f, 0.f};
  #pragma unroll
  for (int g = 0; g < 6; g++) {
    #pragma unroll
    for (int r = 0; r < 4; r++) {
      float pv = __expf(sacc[g][r] - mx[r]);
      sum[r] += pv;
      p_s[w][lhi * 4 + r][g * 16 + l15] = f2bf(pv);
    }
  }
  #pragma unroll
  for (int off = 1; off < 16; off <<= 1) {
    #pragma unroll
    for (int r = 0; r < 4; r++) sum[r] += __shfl_xor(sum[r], off);
  }
  __syncthreads();

  f32x4 oacc[4];
  #pragma unroll
  for (int dg = 0; dg < 4; dg++) oacc[dg] = zero;
  #pragma unroll
  for (int ks = 0; ks < 3; ks++) {
    short8 pa = *(const short8*)&p_s[w][l15][ks * 32 + lhi * 8];
    #pragma unroll
    for (int dg = 0; dg < 4; dg++) {
      short8 vb = *(const short8*)&vt_s[dg * 16 + l15][ks * 32 + lhi * 8];
      oacc[dg] = __builtin_amdgcn_mfma_f32_16x16x32_bf16(pa, vb, oacc[dg], 0, 0, 0);
    }
  }

  unsigned short* ob = aout + ((size_t)b * 4096 + qt * 64 + w * 16) * 768 + h * 64;
  #pragma unroll
  for (int dg = 0; dg < 4; dg++) {
    int d = dg * 16 + l15;
    #pragma unroll
    for (int r = 0; r < 4; r++) {
      ob[(size_t)(lhi * 4 + r) * 768 + d] = f2bf(oacc[dg][r] / sum[r]);
    }
  }
}

extern "C" void kernel_launch(void* const* d_in, const int* in_sizes, int n_in,
                              void* d_out, int out_size, void* d_ws, size_t ws_size,
                              hipStream_t stream) {
  const float* x   = (const float*)d_in[0];
  const float* Wq  = (const float*)d_in[1];
  const float* Wkv = (const float*)d_in[2];
  const float* srw = (const float*)d_in[3];
  const float* srb = (const float*)d_in[4];
  const float* lng = (const float*)d_in[5];
  const float* lnb = (const float*)d_in[6];
  const float* pw  = (const float*)d_in[7];
  const float* pb  = (const float*)d_in[8];

  // Workspace (49.3 MiB peak), liveness-overlapped (same layout as round 4):
  char* ws = (char*)d_ws;
  float* qtab           = (float*)(ws);
  float* ktab           = (float*)(ws + 1048576);
  unsigned short* xb    = (unsigned short*)(ws + 1310720);    // bf16 x; attn_out later
  unsigned short* attno = xb;
  unsigned short* qrope = (unsigned short*)(ws + 13893632);
  unsigned short* part  = (unsigned short*)(ws + 26476544);   // [4][2048][768] bf16
  unsigned short* kr    = (unsigned short*)(ws + 26476544);   // overlays part (dead)
  unsigned short* vr    = (unsigned short*)(ws + 29622272);
  unsigned short* wqb   = (unsigned short*)(ws + 39059456);
  unsigned short* wkvb  = (unsigned short*)(ws + 40239104);
  unsigned short* pwb   = (unsigned short*)(ws + 42598400);
  unsigned short* wsrb  = (unsigned short*)(ws + 43778048);   // [4][768][768] bf16
  unsigned short* xrn   = (unsigned short*)(ws + 48496640);   // [2048][768] bf16

  // 1) all prep in one launch
  k_prep<<<18304, 256, 0, stream>>>(x, Wq, Wkv, pw, srw, qtab, ktab,
                                    xb, wqb, wkvb, pwb, wsrb);
  // 2) merged Q-GEMM (RoPE epilogue -> qrope) + conv split-K (-> part)
  k_g<2><<<768, 256, 0, stream>>>(xb, wqb, wsrb, qrope, part, nullptr, qtab);
  // 3) reduce partials + sr_b + LayerNorm -> xrn
  k_lnr<<<2048, 256, 0, stream>>>(part, srb, lng, lnb, xrn);
  // 4) KV GEMM, RoPE-K + V pack -> kr, vr
  k_g<1><<<dim3(12, 16), 256, 0, stream>>>(xrn, wkvb, nullptr, kr, vr, nullptr, ktab);
  // 5) masked attention -> attno (bf16)
  k_attn<<<dim3(64, 12, 2), 256, 0, stream>>>(qrope, kr, vr, attno);
  // 6) out = attno @ proj_w^T + proj_b -> f32 d_out
  k_g<0><<<dim3(6, 64), 256, 0, stream>>>(attno, pwb, nullptr, d_out, nullptr, pb, nullptr);
}

// Round 6
// 132.285 us; speedup vs baseline: 2.1619x; 1.0131x over previous
//
#include <hip/hip_runtime.h>
#include <hip/hip_bf16.h>
#include <math.h>

typedef __attribute__((ext_vector_type(4))) float f32x4;
typedef __attribute__((ext_vector_type(8))) short short8;
typedef __attribute__((ext_vector_type(8))) unsigned short ushort8;
typedef __attribute__((ext_vector_type(4))) unsigned short ushort4v;

__device__ __forceinline__ unsigned short f2bf(float f) {
  __hip_bfloat16 h = __float2bfloat16(f);
  return *reinterpret_cast<unsigned short*>(&h);
}
__device__ __forceinline__ float bf2f(unsigned short u) {
  unsigned v = ((unsigned)u) << 16;
  return *reinterpret_cast<float*>(&v);
}
__device__ __forceinline__ void async16(const void* g, void* l) {
  __builtin_amdgcn_global_load_lds(
      (__attribute__((address_space(1))) void*)g,
      (__attribute__((address_space(3))) void*)l, 16, 0, 0);
}
#define WAITVM4 { asm volatile("s_waitcnt vmcnt(4)" ::: "memory"); __builtin_amdgcn_sched_barrier(0); }
#define WAITVM0 { asm volatile("s_waitcnt vmcnt(0)" ::: "memory"); __builtin_amdgcn_sched_barrier(0); }

// ---------------- fused prep: RoPE tables + all f32->bf16 casts + sr_w repack ----------------
__global__ __launch_bounds__(256) void k_prep(
    const float* __restrict__ x, const float* __restrict__ Wq,
    const float* __restrict__ Wkv, const float* __restrict__ pw,
    const float* __restrict__ srw,
    float* __restrict__ qtab, float* __restrict__ ktab,
    unsigned short* __restrict__ xb, unsigned short* __restrict__ wqb,
    unsigned short* __restrict__ wkvb, unsigned short* __restrict__ pwb,
    unsigned short* __restrict__ wsrb)
{
  int idx = blockIdx.x * 256 + threadIdx.x;
  if (idx < 131072) {                       // q-table [4096][32]
    int n = idx >> 5, i = idx & 31;
    float freq = powf(10000.0f, -(float)(i >> 1) * (1.0f / 16.0f));
    float pos = (i & 1) ? (float)(n >> 6) : (float)(n & 63);
    float a = pos * freq;
    qtab[idx * 2] = cosf(a);
    qtab[idx * 2 + 1] = sinf(a);
  } else if (idx < 163840) {                // k-table [1024][32]
    int t = idx - 131072;
    int m = t >> 5, i = t & 31;
    float freq = powf(10000.0f, -(float)(i >> 1) * (1.0f / 16.0f));
    float pos = (i & 1) ? (0.5f + 2.0f * (float)(m >> 6)) : (0.5f + 2.0f * (float)(m & 63));
    float a = pos * freq;
    ktab[t * 2] = cosf(a);
    ktab[t * 2 + 1] = sinf(a);
  } else if (idx < 1736704) {               // x cvt (float4 units)
    int g = idx - 163840;
    float4 v = ((const float4*)x)[g];
    ushort4v o; o[0]=f2bf(v.x); o[1]=f2bf(v.y); o[2]=f2bf(v.z); o[3]=f2bf(v.w);
    *(ushort4v*)(xb + g * 4) = o;
  } else if (idx < 1884160) {               // Wq cvt
    int g = idx - 1736704;
    float4 v = ((const float4*)Wq)[g];
    ushort4v o; o[0]=f2bf(v.x); o[1]=f2bf(v.y); o[2]=f2bf(v.z); o[3]=f2bf(v.w);
    *(ushort4v*)(wqb + g * 4) = o;
  } else if (idx < 2179072) {               // Wkv cvt
    int g = idx - 1884160;
    float4 v = ((const float4*)Wkv)[g];
    ushort4v o; o[0]=f2bf(v.x); o[1]=f2bf(v.y); o[2]=f2bf(v.z); o[3]=f2bf(v.w);
    *(ushort4v*)(wkvb + g * 4) = o;
  } else if (idx < 2326528) {               // proj_w cvt
    int g = idx - 2179072;
    float4 v = ((const float4*)pw)[g];
    ushort4v o; o[0]=f2bf(v.x); o[1]=f2bf(v.y); o[2]=f2bf(v.z); o[3]=f2bf(v.w);
    *(ushort4v*)(pwb + g * 4) = o;
  } else if (idx < 4685824) {               // sr_w (O,C,2,2) -> [patch][O][C]
    int g = idx - 2326528;
    int o = g / 3072;
    int rem = g - o * 3072;
    int c = rem >> 2, patch = rem & 3;
    wsrb[(size_t)patch * 589824 + o * 768 + c] = f2bf(srw[g]);
  }
}

// ---------------- GEMM, 128x128 tile, BK=32, 3-buffer counted-vmcnt pipeline ----------------
// MODE 0: proj  (384 blocks) : O0=f32 d_out (+bias), swapped-operand MFMA, coalesced stores
// MODE 1: kv    (192 blocks) : O0=kr (RoPE), O1=vr
// MODE 2: qconv (768 blocks) : tile<384 Q->O0=qrope (RoPE); else conv patch->O1=part (bf16)
// K = 768 always (NT=24).
template<int MODE>
__global__ __launch_bounds__(256) void k_g(
    const unsigned short* __restrict__ A, const unsigned short* __restrict__ W,
    const unsigned short* __restrict__ W2,
    void* __restrict__ O0, void* __restrict__ O1,
    const float* __restrict__ bias, const float* __restrict__ tab)
{
  __shared__ __align__(16) unsigned short As[3][128][32];
  __shared__ __align__(16) unsigned short Ws[3][128][32];
  const int tid = threadIdx.x, lane = tid & 63, wid = tid >> 6;
  const int wr = (wid >> 1) * 64, wc = (wid & 1) * 64;
  const int l15 = lane & 15, lhi = lane >> 4;
  const int K = 768, NT = 24;

  // XCD-chunked bijective swizzle (grid % 8 == 0 for all modes)
  const int NWG = (MODE == 2) ? 768 : (MODE == 1 ? 192 : 384);
  const int tile = ((int)blockIdx.x & 7) * (NWG >> 3) + ((int)blockIdx.x >> 3);

  int cm, cn, patch = 0;
  bool isconv = false;
  if (MODE == 2) {
    if (tile < 384) { cm = (tile / 6) * 128; cn = (tile % 6) * 128; }
    else {
      int c = tile - 384; isconv = true;
      patch = c / 96; int r = c - patch * 96;
      cm = (r / 6) * 128; cn = (r % 6) * 128;
    }
  } else if (MODE == 1) {
    cm = (tile / 12) * 128; cn = (tile % 12) * 128;
  } else {
    cm = (tile / 6) * 128; cn = (tile % 6) * 128;
  }

  size_t aoff0, aoff1;
  {
    int r0 = cm + wid * 32 + (lane >> 2);
    int r1 = r0 + 16;
    if (MODE == 2 && isconv) {
      int kh = patch >> 1, kw = patch & 1;
      int b0 = r0 >> 10, p0 = r0 & 1023;
      int b1 = r1 >> 10, p1 = r1 & 1023;
      r0 = b0 * 4096 + (2 * (p0 >> 5) + kh) * 64 + 2 * (p0 & 31) + kw;
      r1 = b1 * 4096 + (2 * (p1 >> 5) + kh) * 64 + 2 * (p1 & 31) + kw;
    }
    aoff0 = (size_t)r0 * K + (lane & 3) * 8;
    aoff1 = (size_t)r1 * K + (lane & 3) * 8;
  }
  const unsigned short* wbase = (MODE == 2 && isconv) ? (W2 + (size_t)patch * 589824) : W;
  size_t woff0 = (size_t)(cn + wid * 32 + (lane >> 2)) * K + (lane & 3) * 8;
  size_t woff1 = woff0 + (size_t)16 * K;

#define STAGE(bi, kt) { \
    async16(A + aoff0 + (kt) * 32,     &As[bi][wid * 32][0]);      \
    async16(A + aoff1 + (kt) * 32,     &As[bi][wid * 32 + 16][0]); \
    async16(wbase + woff0 + (kt) * 32, &Ws[bi][wid * 32][0]);      \
    async16(wbase + woff1 + (kt) * 32, &Ws[bi][wid * 32 + 16][0]); }

  f32x4 zero = {0.f, 0.f, 0.f, 0.f};
  f32x4 acc[4][4];
  #pragma unroll
  for (int i = 0; i < 4; i++)
    #pragma unroll
    for (int j = 0; j < 4; j++) acc[i][j] = zero;

  STAGE(0, 0);
  STAGE(1, 1);

  for (int kt = 0; kt < NT; ++kt) {
    if (kt + 1 < NT) WAITVM4 else WAITVM0;   // own stage(kt) landed; stage(kt+1) may fly
    __builtin_amdgcn_s_barrier();            // all waves' stage(kt) landed
    __builtin_amdgcn_sched_barrier(0);
    const int bi = kt % 3;
    if (kt + 2 < NT) STAGE((kt + 2) % 3, kt + 2);
    short8 af[4], wf[4];
    #pragma unroll
    for (int m = 0; m < 4; m++) af[m] = *(const short8*)&As[bi][wr + m * 16 + l15][lhi * 8];
    #pragma unroll
    for (int n = 0; n < 4; n++) wf[n] = *(const short8*)&Ws[bi][wc + n * 16 + l15][lhi * 8];
    #pragma unroll
    for (int m = 0; m < 4; m++)
      #pragma unroll
      for (int n = 0; n < 4; n++) {
        if (MODE == 0)
          acc[m][n] = __builtin_amdgcn_mfma_f32_16x16x32_bf16(wf[n], af[m], acc[m][n], 0, 0, 0);
        else
          acc[m][n] = __builtin_amdgcn_mfma_f32_16x16x32_bf16(af[m], wf[n], acc[m][n], 0, 0, 0);
      }
  }
#undef STAGE

  if (MODE == 0) {
    // swapped operands: acc[m][n] holds rows = A-rows (l15), 4 consecutive out-cols (lhi*4+r)
    float* O = (float*)O0;
    #pragma unroll
    for (int n = 0; n < 4; n++) {
      int colb = cn + wc + n * 16 + lhi * 4;
      f32x4 bv = *(const f32x4*)&bias[colb];
      #pragma unroll
      for (int m = 0; m < 4; m++) {
        int row = cm + wr + m * 16 + l15;
        f32x4 v = acc[m][n] + bv;
        *(f32x4*)&O[(size_t)row * 768 + colb] = v;
      }
    }
  } else if (MODE == 1) {
    // cols 0..767 -> K (RoPE), 768..1535 -> V
    unsigned short* kr = (unsigned short*)O0;
    unsigned short* vr = (unsigned short*)O1;
    const float2* t2 = (const float2*)tab;
    #pragma unroll
    for (int n = 0; n < 4; n++) {
      int col = cn + wc + n * 16 + l15;
      bool isk = (col < 768);
      int c2 = isk ? col : col - 768;
      int hh = c2 >> 6, d = c2 & 63, i = d >> 1;
      #pragma unroll
      for (int m = 0; m < 4; m++)
        #pragma unroll
        for (int r = 0; r < 4; r++) {
          int row = cm + wr + m * 16 + lhi * 4 + r;
          int bb = row >> 10, mm = row & 1023;
          float v = acc[m][n][r];
          float p = __shfl_xor(v, 1);
          size_t o = ((size_t)(bb * 12 + hh) * 1024 + mm) * 64 + d;
          if (isk) {
            float2 cs = t2[mm * 32 + i];
            float ov = (d & 1) ? (p * cs.y + v * cs.x) : (v * cs.x - p * cs.y);
            kr[o] = f2bf(ov);
          } else {
            vr[o] = f2bf(v);
          }
        }
    }
  } else {
    if (!isconv) {
      unsigned short* qr = (unsigned short*)O0;
      const float2* t2 = (const float2*)tab;
      #pragma unroll
      for (int n = 0; n < 4; n++) {
        int col = cn + wc + n * 16 + l15;
        int hh = col >> 6, d = col & 63, i = d >> 1;
        #pragma unroll
        for (int m = 0; m < 4; m++)
          #pragma unroll
          for (int r = 0; r < 4; r++) {
            int row = cm + wr + m * 16 + lhi * 4 + r;
            int bb = row >> 12, np = row & 4095;
            float v = acc[m][n][r];
            float p = __shfl_xor(v, 1);
            float2 cs = t2[np * 32 + i];
            float o = (d & 1) ? (p * cs.y + v * cs.x) : (v * cs.x - p * cs.y);
            qr[((size_t)(bb * 12 + hh) * 4096 + np) * 64 + d] = f2bf(o);
          }
      }
    } else {
      unsigned short* O = (unsigned short*)O1 + (size_t)patch * 2048 * 768;
      #pragma unroll
      for (int n = 0; n < 4; n++) {
        int col = cn + wc + n * 16 + l15;
        #pragma unroll
        for (int m = 0; m < 4; m++)
          #pragma unroll
          for (int r = 0; r < 4; r++) {
            int row = cm + wr + m * 16 + lhi * 4 + r;
            O[(size_t)row * 768 + col] = f2bf(acc[m][n][r]);
          }
      }
    }
  }
}

// ---------------- fused partial-reduce + bias + LayerNorm -> bf16 ----------------
__global__ __launch_bounds__(256) void k_lnr(const unsigned short* __restrict__ part,
    const float* __restrict__ srb, const float* __restrict__ g,
    const float* __restrict__ b, unsigned short* __restrict__ out) {
  int row = blockIdx.x;
  int t = threadIdx.x;
  float v[3];
  #pragma unroll
  for (int j = 0; j < 3; j++) {
    int c = t + j * 256;
    float s = srb[c];
    #pragma unroll
    for (int p = 0; p < 4; p++)
      s += bf2f(part[((size_t)p * 2048 + row) * 768 + c]);
    v[j] = s;
  }
  float s = v[0] + v[1] + v[2];
  float s2 = v[0] * v[0] + v[1] * v[1] + v[2] * v[2];
  #pragma unroll
  for (int off = 1; off < 64; off <<= 1) {
    s += __shfl_xor(s, off);
    s2 += __shfl_xor(s2, off);
  }
  __shared__ float ss[4], ss2[4];
  int w = t >> 6;
  if ((t & 63) == 0) { ss[w] = s; ss2[w] = s2; }
  __syncthreads();
  s = ss[0] + ss[1] + ss[2] + ss[3];
  s2 = ss2[0] + ss2[1] + ss2[2] + ss2[3];
  float mu = s * (1.0f / 768.0f);
  float var = s2 * (1.0f / 768.0f) - mu * mu;
  float rstd = rsqrtf(var + 1e-5f);
  unsigned short* o = out + (size_t)row * 768;
  #pragma unroll
  for (int j = 0; j < 3; j++) {
    int c = t + j * 256;
    o[c] = f2bf((v[j] - mu) * rstd * g[c] + b[c]);
  }
}

// ---------------- masked attention: per (b,h,64-query tile), bf16 out ----------------
__global__ __launch_bounds__(256) void k_attn(
    const unsigned short* __restrict__ qr,
    const unsigned short* __restrict__ kr,
    const unsigned short* __restrict__ vr,
    unsigned short* __restrict__ aout)
{
  __shared__ __align__(16) unsigned short kt_s[96][72];
  __shared__ __align__(16) unsigned short vt_s[64][104];
  __shared__ __align__(16) unsigned short p_s[4][16][104];

  const int qt = blockIdx.x;
  const int h = blockIdx.y;
  const int b = blockIdx.z;
  const int bh = b * 12 + h;
  const int tid = threadIdx.x, lane = tid & 63, w = tid >> 6;
  const int l15 = lane & 15, lhi = lane >> 4;

  const unsigned short* kg = kr + (size_t)bh * 1024 * 64;
  #pragma unroll
  for (int it = 0; it < 3; it++) {
    int ch = it * 256 + tid;
    int row = ch >> 3, c8 = (ch & 7) * 8;
    *(ushort8*)&kt_s[row][c8] = *(const ushort8*)(kg + row * 64 + c8);
  }
  const unsigned short* vg = vr + (size_t)bh * 1024 * 64;
  #pragma unroll
  for (int it = 0; it < 24; it++) {
    int e = it * 256 + tid;
    int row = e >> 6, d = e & 63;
    vt_s[d][row] = vg[row * 64 + d];
  }
  __syncthreads();

  const unsigned short* qg = qr + (size_t)bh * 4096 * 64
                           + (size_t)(qt * 64 + w * 16 + l15) * 64 + lhi * 8;
  short8 qf0 = *(const short8*)qg;
  short8 qf1 = *(const short8*)(qg + 32);

  f32x4 zero = {0.f, 0.f, 0.f, 0.f};
  f32x4 sacc[6];
  #pragma unroll
  for (int g = 0; g < 6; g++) sacc[g] = zero;
  #pragma unroll
  for (int g = 0; g < 6; g++) {
    short8 kf0 = *(const short8*)&kt_s[g * 16 + l15][lhi * 8];
    short8 kf1 = *(const short8*)&kt_s[g * 16 + l15][32 + lhi * 8];
    sacc[g] = __builtin_amdgcn_mfma_f32_16x16x32_bf16(qf0, kf0, sacc[g], 0, 0, 0);
    sacc[g] = __builtin_amdgcn_mfma_f32_16x16x32_bf16(qf1, kf1, sacc[g], 0, 0, 0);
  }

  int visv[4];
  #pragma unroll
  for (int r = 0; r < 4; r++) {
    int n = qt * 64 + w * 16 + lhi * 4 + r;
    visv[r] = 2 * (n >> 7) + (((n >> 6) + ((n & 63) << 6)) >> 7) + 1;
  }

  float mx[4] = {-INFINITY, -INFINITY, -INFINITY, -INFINITY};
  #pragma unroll
  for (int g = 0; g < 6; g++) {
    int key = g * 16 + l15;
    #pragma unroll
    for (int r = 0; r < 4; r++) {
      float s = (key < visv[r]) ? sacc[g][r] * 0.125f : -INFINITY;
      sacc[g][r] = s;
      mx[r] = fmaxf(mx[r], s);
    }
  }
  #pragma unroll
  for (int off = 1; off < 16; off <<= 1) {
    #pragma unroll
    for (int r = 0; r < 4; r++) mx[r] = fmaxf(mx[r], __shfl_xor(mx[r], off));
  }
  float sum[4] = {0.f, 0.f, 0.f, 0.f};
  #pragma unroll
  for (int g = 0; g < 6; g++) {
    #pragma unroll
    for (int r = 0; r < 4; r++) {
      float pv = __expf(sacc[g][r] - mx[r]);
      sum[r] += pv;
      p_s[w][lhi * 4 + r][g * 16 + l15] = f2bf(pv);
    }
  }
  #pragma unroll
  for (int off = 1; off < 16; off <<= 1) {
    #pragma unroll
    for (int r = 0; r < 4; r++) sum[r] += __shfl_xor(sum[r], off);
  }
  __syncthreads();

  f32x4 oacc[4];
  #pragma unroll
  for (int dg = 0; dg < 4; dg++) oacc[dg] = zero;
  #pragma unroll
  for (int ks = 0; ks < 3; ks++) {
    short8 pa = *(const short8*)&p_s[w][l15][ks * 32 + lhi * 8];
    #pragma unroll
    for (int dg = 0; dg < 4; dg++) {
      short8 vb = *(const short8*)&vt_s[dg * 16 + l15][ks * 32 + lhi * 8];
      oacc[dg] = __builtin_amdgcn_mfma_f32_16x16x32_bf16(pa, vb, oacc[dg], 0, 0, 0);
    }
  }

  unsigned short* ob = aout + ((size_t)b * 4096 + qt * 64 + w * 16) * 768 + h * 64;
  #pragma unroll
  for (int dg = 0; dg < 4; dg++) {
    int d = dg * 16 + l15;
    #pragma unroll
    for (int r = 0; r < 4; r++) {
      ob[(size_t)(lhi * 4 + r) * 768 + d] = f2bf(oacc[dg][r] / sum[r]);
    }
  }
}

extern "C" void kernel_launch(void* const* d_in, const int* in_sizes, int n_in,
                              void* d_out, int out_size, void* d_ws, size_t ws_size,
                              hipStream_t stream) {
  const float* x   = (const float*)d_in[0];
  const float* Wq  = (const float*)d_in[1];
  const float* Wkv = (const float*)d_in[2];
  const float* srw = (const float*)d_in[3];
  const float* srb = (const float*)d_in[4];
  const float* lng = (const float*)d_in[5];
  const float* lnb = (const float*)d_in[6];
  const float* pw  = (const float*)d_in[7];
  const float* pb  = (const float*)d_in[8];

  char* ws = (char*)d_ws;
  float* qtab           = (float*)(ws);
  float* ktab           = (float*)(ws + 1048576);
  unsigned short* xb    = (unsigned short*)(ws + 1310720);    // bf16 x; attn_out later
  unsigned short* attno = xb;
  unsigned short* qrope = (unsigned short*)(ws + 13893632);
  unsigned short* part  = (unsigned short*)(ws + 26476544);   // [4][2048][768] bf16
  unsigned short* kr    = (unsigned short*)(ws + 26476544);   // overlays part (dead)
  unsigned short* vr    = (unsigned short*)(ws + 29622272);
  unsigned short* wqb   = (unsigned short*)(ws + 39059456);
  unsigned short* wkvb  = (unsigned short*)(ws + 40239104);
  unsigned short* pwb   = (unsigned short*)(ws + 42598400);
  unsigned short* wsrb  = (unsigned short*)(ws + 43778048);   // [4][768][768] bf16
  unsigned short* xrn   = (unsigned short*)(ws + 48496640);   // [2048][768] bf16

  k_prep<<<18304, 256, 0, stream>>>(x, Wq, Wkv, pw, srw, qtab, ktab,
                                    xb, wqb, wkvb, pwb, wsrb);
  k_g<2><<<768, 256, 0, stream>>>(xb, wqb, wsrb, qrope, part, nullptr, qtab);
  k_lnr<<<2048, 256, 0, stream>>>(part, srb, lng, lnb, xrn);
  k_g<1><<<192, 256, 0, stream>>>(xrn, wkvb, nullptr, kr, vr, nullptr, ktab);
  k_attn<<<dim3(64, 12, 2), 256, 0, stream>>>(qrope, kr, vr, attno);
  k_g<0><<<384, 256, 0, stream>>>(attno, pwb, nullptr, d_out, nullptr, pb, nullptr);
}

// Round 7
// 131.517 us; speedup vs baseline: 2.1745x; 1.0058x over previous
//
#include <hip/hip_runtime.h>
#include <hip/hip_bf16.h>
#include <math.h>

typedef __attribute__((ext_vector_type(4))) float f32x4;
typedef __attribute__((ext_vector_type(8))) short short8;
typedef __attribute__((ext_vector_type(8))) unsigned short ushort8;
typedef __attribute__((ext_vector_type(4))) unsigned short ushort4v;

__device__ __forceinline__ unsigned short f2bf(float f) {
  __hip_bfloat16 h = __float2bfloat16(f);
  return *reinterpret_cast<unsigned short*>(&h);
}
__device__ __forceinline__ float bf2f(unsigned short u) {
  unsigned v = ((unsigned)u) << 16;
  return *reinterpret_cast<float*>(&v);
}
__device__ __forceinline__ void async16(const void* g, void* l) {
  __builtin_amdgcn_global_load_lds(
      (__attribute__((address_space(1))) void*)g,
      (__attribute__((address_space(3))) void*)l, 16, 0, 0);
}
#define WAITVM4 { asm volatile("s_waitcnt vmcnt(4)" ::: "memory"); __builtin_amdgcn_sched_barrier(0); }
#define WAITVM0 { asm volatile("s_waitcnt vmcnt(0)" ::: "memory"); __builtin_amdgcn_sched_barrier(0); }

// ---------------- fused prep: RoPE tables + all f32->bf16 casts + sr_w repack ----------------
__global__ __launch_bounds__(256) void k_prep(
    const float* __restrict__ x, const float* __restrict__ Wq,
    const float* __restrict__ Wkv, const float* __restrict__ pw,
    const float* __restrict__ srw,
    float* __restrict__ qtab, float* __restrict__ ktab,
    unsigned short* __restrict__ xb, unsigned short* __restrict__ wqb,
    unsigned short* __restrict__ wkvb, unsigned short* __restrict__ pwb,
    unsigned short* __restrict__ wsrb)
{
  int idx = blockIdx.x * 256 + threadIdx.x;
  if (idx < 131072) {                       // q-table [4096][32]
    int n = idx >> 5, i = idx & 31;
    float freq = powf(10000.0f, -(float)(i >> 1) * (1.0f / 16.0f));
    float pos = (i & 1) ? (float)(n >> 6) : (float)(n & 63);
    float a = pos * freq;
    qtab[idx * 2] = cosf(a);
    qtab[idx * 2 + 1] = sinf(a);
  } else if (idx < 163840) {                // k-table [1024][32]
    int t = idx - 131072;
    int m = t >> 5, i = t & 31;
    float freq = powf(10000.0f, -(float)(i >> 1) * (1.0f / 16.0f));
    float pos = (i & 1) ? (0.5f + 2.0f * (float)(m >> 6)) : (0.5f + 2.0f * (float)(m & 63));
    float a = pos * freq;
    ktab[t * 2] = cosf(a);
    ktab[t * 2 + 1] = sinf(a);
  } else if (idx < 1736704) {               // x cvt (float4 units)
    int g = idx - 163840;
    float4 v = ((const float4*)x)[g];
    ushort4v o; o[0]=f2bf(v.x); o[1]=f2bf(v.y); o[2]=f2bf(v.z); o[3]=f2bf(v.w);
    *(ushort4v*)(xb + g * 4) = o;
  } else if (idx < 1884160) {               // Wq cvt
    int g = idx - 1736704;
    float4 v = ((const float4*)Wq)[g];
    ushort4v o; o[0]=f2bf(v.x); o[1]=f2bf(v.y); o[2]=f2bf(v.z); o[3]=f2bf(v.w);
    *(ushort4v*)(wqb + g * 4) = o;
  } else if (idx < 2179072) {               // Wkv cvt
    int g = idx - 1884160;
    float4 v = ((const float4*)Wkv)[g];
    ushort4v o; o[0]=f2bf(v.x); o[1]=f2bf(v.y); o[2]=f2bf(v.z); o[3]=f2bf(v.w);
    *(ushort4v*)(wkvb + g * 4) = o;
  } else if (idx < 2326528) {               // proj_w cvt
    int g = idx - 2179072;
    float4 v = ((const float4*)pw)[g];
    ushort4v o; o[0]=f2bf(v.x); o[1]=f2bf(v.y); o[2]=f2bf(v.z); o[3]=f2bf(v.w);
    *(ushort4v*)(pwb + g * 4) = o;
  } else if (idx < 4685824) {               // sr_w (O,C,2,2) -> [patch][O][C]
    int g = idx - 2326528;
    int o = g / 3072;
    int rem = g - o * 3072;
    int c = rem >> 2, patch = rem & 3;
    wsrb[(size_t)patch * 589824 + o * 768 + c] = f2bf(srw[g]);
  }
}

// ---------------- GEMM, 128x128 tile, BK=32, 3-buffer counted-vmcnt pipeline ----------------
// __launch_bounds__(256,4): force <=128 total regs/wave -> 4 waves/SIMD -> LDS-bound
// residency of 3 blocks/CU (12 waves/CU) instead of the 168-reg 2-wave/SIMD regime.
// MODE 0: proj  (384 blocks) : O0=f32 d_out (+bias), swapped-operand MFMA, coalesced stores
// MODE 1: kv    (192 blocks) : O0=kr (RoPE), O1=vr
// MODE 2: qconv (768 blocks) : tile<384 Q->O0=qrope (RoPE); else conv patch->O1=part (bf16)
template<int MODE>
__global__ __launch_bounds__(256, 4) void k_g(
    const unsigned short* __restrict__ A, const unsigned short* __restrict__ W,
    const unsigned short* __restrict__ W2,
    void* __restrict__ O0, void* __restrict__ O1,
    const float* __restrict__ bias, const float* __restrict__ tab)
{
  __shared__ __align__(16) unsigned short As[3][128][32];
  __shared__ __align__(16) unsigned short Ws[3][128][32];
  const int tid = threadIdx.x, lane = tid & 63, wid = tid >> 6;
  const int wr = (wid >> 1) * 64, wc = (wid & 1) * 64;
  const int l15 = lane & 15, lhi = lane >> 4;
  const int K = 768, NT = 24;

  // XCD-chunked bijective swizzle (grid % 8 == 0 for all modes)
  const int NWG = (MODE == 2) ? 768 : (MODE == 1 ? 192 : 384);
  const int tile = ((int)blockIdx.x & 7) * (NWG >> 3) + ((int)blockIdx.x >> 3);

  int cm, cn, patch = 0;
  bool isconv = false;
  if (MODE == 2) {
    if (tile < 384) { cm = (tile / 6) * 128; cn = (tile % 6) * 128; }
    else {
      int c = tile - 384; isconv = true;
      patch = c / 96; int r = c - patch * 96;
      cm = (r / 6) * 128; cn = (r % 6) * 128;
    }
  } else if (MODE == 1) {
    cm = (tile / 12) * 128; cn = (tile % 12) * 128;
  } else {
    cm = (tile / 6) * 128; cn = (tile % 6) * 128;
  }

  size_t aoff0, aoff1;
  {
    int r0 = cm + wid * 32 + (lane >> 2);
    int r1 = r0 + 16;
    if (MODE == 2 && isconv) {
      int kh = patch >> 1, kw = patch & 1;
      int b0 = r0 >> 10, p0 = r0 & 1023;
      int b1 = r1 >> 10, p1 = r1 & 1023;
      r0 = b0 * 4096 + (2 * (p0 >> 5) + kh) * 64 + 2 * (p0 & 31) + kw;
      r1 = b1 * 4096 + (2 * (p1 >> 5) + kh) * 64 + 2 * (p1 & 31) + kw;
    }
    aoff0 = (size_t)r0 * K + (lane & 3) * 8;
    aoff1 = (size_t)r1 * K + (lane & 3) * 8;
  }
  const unsigned short* wbase = (MODE == 2 && isconv) ? (W2 + (size_t)patch * 589824) : W;
  size_t woff0 = (size_t)(cn + wid * 32 + (lane >> 2)) * K + (lane & 3) * 8;
  size_t woff1 = woff0 + (size_t)16 * K;

#define STAGE(bi, kt) { \
    async16(A + aoff0 + (kt) * 32,     &As[bi][wid * 32][0]);      \
    async16(A + aoff1 + (kt) * 32,     &As[bi][wid * 32 + 16][0]); \
    async16(wbase + woff0 + (kt) * 32, &Ws[bi][wid * 32][0]);      \
    async16(wbase + woff1 + (kt) * 32, &Ws[bi][wid * 32 + 16][0]); }

  f32x4 zero = {0.f, 0.f, 0.f, 0.f};
  f32x4 acc[4][4];
  #pragma unroll
  for (int i = 0; i < 4; i++)
    #pragma unroll
    for (int j = 0; j < 4; j++) acc[i][j] = zero;

  STAGE(0, 0);
  STAGE(1, 1);

  for (int kt = 0; kt < NT; ++kt) {
    if (kt + 1 < NT) WAITVM4 else WAITVM0;   // own stage(kt) landed; stage(kt+1) may fly
    __builtin_amdgcn_s_barrier();            // all waves' stage(kt) landed
    __builtin_amdgcn_sched_barrier(0);
    const int bi = kt % 3;
    if (kt + 2 < NT) STAGE((kt + 2) % 3, kt + 2);
    short8 af[4], wf[4];
    #pragma unroll
    for (int m = 0; m < 4; m++) af[m] = *(const short8*)&As[bi][wr + m * 16 + l15][lhi * 8];
    #pragma unroll
    for (int n = 0; n < 4; n++) wf[n] = *(const short8*)&Ws[bi][wc + n * 16 + l15][lhi * 8];
    #pragma unroll
    for (int m = 0; m < 4; m++)
      #pragma unroll
      for (int n = 0; n < 4; n++) {
        if (MODE == 0)
          acc[m][n] = __builtin_amdgcn_mfma_f32_16x16x32_bf16(wf[n], af[m], acc[m][n], 0, 0, 0);
        else
          acc[m][n] = __builtin_amdgcn_mfma_f32_16x16x32_bf16(af[m], wf[n], acc[m][n], 0, 0, 0);
      }
  }
#undef STAGE

  if (MODE == 0) {
    // swapped operands: acc[m][n] holds rows = A-rows (l15), 4 consecutive out-cols (lhi*4+r)
    float* O = (float*)O0;
    #pragma unroll
    for (int n = 0; n < 4; n++) {
      int colb = cn + wc + n * 16 + lhi * 4;
      f32x4 bv = *(const f32x4*)&bias[colb];
      #pragma unroll
      for (int m = 0; m < 4; m++) {
        int row = cm + wr + m * 16 + l15;
        f32x4 v = acc[m][n] + bv;
        *(f32x4*)&O[(size_t)row * 768 + colb] = v;
      }
    }
  } else if (MODE == 1) {
    // cols 0..767 -> K (RoPE), 768..1535 -> V
    unsigned short* kr = (unsigned short*)O0;
    unsigned short* vr = (unsigned short*)O1;
    const float2* t2 = (const float2*)tab;
    #pragma unroll
    for (int n = 0; n < 4; n++) {
      int col = cn + wc + n * 16 + l15;
      bool isk = (col < 768);
      int c2 = isk ? col : col - 768;
      int hh = c2 >> 6, d = c2 & 63, i = d >> 1;
      #pragma unroll
      for (int m = 0; m < 4; m++)
        #pragma unroll
        for (int r = 0; r < 4; r++) {
          int row = cm + wr + m * 16 + lhi * 4 + r;
          int bb = row >> 10, mm = row & 1023;
          float v = acc[m][n][r];
          float p = __shfl_xor(v, 1);
          size_t o = ((size_t)(bb * 12 + hh) * 1024 + mm) * 64 + d;
          if (isk) {
            float2 cs = t2[mm * 32 + i];
            float ov = (d & 1) ? (p * cs.y + v * cs.x) : (v * cs.x - p * cs.y);
            kr[o] = f2bf(ov);
          } else {
            vr[o] = f2bf(v);
          }
        }
    }
  } else {
    if (!isconv) {
      unsigned short* qr = (unsigned short*)O0;
      const float2* t2 = (const float2*)tab;
      #pragma unroll
      for (int n = 0; n < 4; n++) {
        int col = cn + wc + n * 16 + l15;
        int hh = col >> 6, d = col & 63, i = d >> 1;
        #pragma unroll
        for (int m = 0; m < 4; m++)
          #pragma unroll
          for (int r = 0; r < 4; r++) {
            int row = cm + wr + m * 16 + lhi * 4 + r;
            int bb = row >> 12, np = row & 4095;
            float v = acc[m][n][r];
            float p = __shfl_xor(v, 1);
            float2 cs = t2[np * 32 + i];
            float o = (d & 1) ? (p * cs.y + v * cs.x) : (v * cs.x - p * cs.y);
            qr[((size_t)(bb * 12 + hh) * 4096 + np) * 64 + d] = f2bf(o);
          }
      }
    } else {
      unsigned short* O = (unsigned short*)O1 + (size_t)patch * 2048 * 768;
      #pragma unroll
      for (int n = 0; n < 4; n++) {
        int col = cn + wc + n * 16 + l15;
        #pragma unroll
        for (int m = 0; m < 4; m++)
          #pragma unroll
          for (int r = 0; r < 4; r++) {
            int row = cm + wr + m * 16 + lhi * 4 + r;
            O[(size_t)row * 768 + col] = f2bf(acc[m][n][r]);
          }
      }
    }
  }
}

// ---------------- fused partial-reduce + bias + LayerNorm -> bf16 ----------------
__global__ __launch_bounds__(256) void k_lnr(const unsigned short* __restrict__ part,
    const float* __restrict__ srb, const float* __restrict__ g,
    const float* __restrict__ b, unsigned short* __restrict__ out) {
  int row = blockIdx.x;
  int t = threadIdx.x;
  float v[3];
  #pragma unroll
  for (int j = 0; j < 3; j++) {
    int c = t + j * 256;
    float s = srb[c];
    #pragma unroll
    for (int p = 0; p < 4; p++)
      s += bf2f(part[((size_t)p * 2048 + row) * 768 + c]);
    v[j] = s;
  }
  float s = v[0] + v[1] + v[2];
  float s2 = v[0] * v[0] + v[1] * v[1] + v[2] * v[2];
  #pragma unroll
  for (int off = 1; off < 64; off <<= 1) {
    s += __shfl_xor(s, off);
    s2 += __shfl_xor(s2, off);
  }
  __shared__ float ss[4], ss2[4];
  int w = t >> 6;
  if ((t & 63) == 0) { ss[w] = s; ss2[w] = s2; }
  __syncthreads();
  s = ss[0] + ss[1] + ss[2] + ss[3];
  s2 = ss2[0] + ss2[1] + ss2[2] + ss2[3];
  float mu = s * (1.0f / 768.0f);
  float var = s2 * (1.0f / 768.0f) - mu * mu;
  float rstd = rsqrtf(var + 1e-5f);
  unsigned short* o = out + (size_t)row * 768;
  #pragma unroll
  for (int j = 0; j < 3; j++) {
    int c = t + j * 256;
    o[c] = f2bf((v[j] - mu) * rstd * g[c] + b[c]);
  }
}

// ---------------- masked attention: per (b,h,64-query tile), bf16 out ----------------
__global__ __launch_bounds__(256) void k_attn(
    const unsigned short* __restrict__ qr,
    const unsigned short* __restrict__ kr,
    const unsigned short* __restrict__ vr,
    unsigned short* __restrict__ aout)
{
  __shared__ __align__(16) unsigned short kt_s[96][72];
  __shared__ __align__(16) unsigned short vt_s[64][104];
  __shared__ __align__(16) unsigned short p_s[4][16][104];

  const int qt = blockIdx.x;
  const int h = blockIdx.y;
  const int b = blockIdx.z;
  const int bh = b * 12 + h;
  const int tid = threadIdx.x, lane = tid & 63, w = tid >> 6;
  const int l15 = lane & 15, lhi = lane >> 4;

  const unsigned short* kg = kr + (size_t)bh * 1024 * 64;
  #pragma unroll
  for (int it = 0; it < 3; it++) {
    int ch = it * 256 + tid;
    int row = ch >> 3, c8 = (ch & 7) * 8;
    *(ushort8*)&kt_s[row][c8] = *(const ushort8*)(kg + row * 64 + c8);
  }
  const unsigned short* vg = vr + (size_t)bh * 1024 * 64;
  #pragma unroll
  for (int it = 0; it < 24; it++) {
    int e = it * 256 + tid;
    int row = e >> 6, d = e & 63;
    vt_s[d][row] = vg[row * 64 + d];
  }
  __syncthreads();

  const unsigned short* qg = qr + (size_t)bh * 4096 * 64
                           + (size_t)(qt * 64 + w * 16 + l15) * 64 + lhi * 8;
  short8 qf0 = *(const short8*)qg;
  short8 qf1 = *(const short8*)(qg + 32);

  f32x4 zero = {0.f, 0.f, 0.f, 0.f};
  f32x4 sacc[6];
  #pragma unroll
  for (int g = 0; g < 6; g++) sacc[g] = zero;
  #pragma unroll
  for (int g = 0; g < 6; g++) {
    short8 kf0 = *(const short8*)&kt_s[g * 16 + l15][lhi * 8];
    short8 kf1 = *(const short8*)&kt_s[g * 16 + l15][32 + lhi * 8];
    sacc[g] = __builtin_amdgcn_mfma_f32_16x16x32_bf16(qf0, kf0, sacc[g], 0, 0, 0);
    sacc[g] = __builtin_amdgcn_mfma_f32_16x16x32_bf16(qf1, kf1, sacc[g], 0, 0, 0);
  }

  int visv[4];
  #pragma unroll
  for (int r = 0; r < 4; r++) {
    int n = qt * 64 + w * 16 + lhi * 4 + r;
    visv[r] = 2 * (n >> 7) + (((n >> 6) + ((n & 63) << 6)) >> 7) + 1;
  }

  float mx[4] = {-INFINITY, -INFINITY, -INFINITY, -INFINITY};
  #pragma unroll
  for (int g = 0; g < 6; g++) {
    int key = g * 16 + l15;
    #pragma unroll
    for (int r = 0; r < 4; r++) {
      float s = (key < visv[r]) ? sacc[g][r] * 0.125f : -INFINITY;
      sacc[g][r] = s;
      mx[r] = fmaxf(mx[r], s);
    }
  }
  #pragma unroll
  for (int off = 1; off < 16; off <<= 1) {
    #pragma unroll
    for (int r = 0; r < 4; r++) mx[r] = fmaxf(mx[r], __shfl_xor(mx[r], off));
  }
  float sum[4] = {0.f, 0.f, 0.f, 0.f};
  #pragma unroll
  for (int g = 0; g < 6; g++) {
    #pragma unroll
    for (int r = 0; r < 4; r++) {
      float pv = __expf(sacc[g][r] - mx[r]);
      sum[r] += pv;
      p_s[w][lhi * 4 + r][g * 16 + l15] = f2bf(pv);
    }
  }
  #pragma unroll
  for (int off = 1; off < 16; off <<= 1) {
    #pragma unroll
    for (int r = 0; r < 4; r++) sum[r] += __shfl_xor(sum[r], off);
  }
  __syncthreads();

  f32x4 oacc[4];
  #pragma unroll
  for (int dg = 0; dg < 4; dg++) oacc[dg] = zero;
  #pragma unroll
  for (int ks = 0; ks < 3; ks++) {
    short8 pa = *(const short8*)&p_s[w][l15][ks * 32 + lhi * 8];
    #pragma unroll
    for (int dg = 0; dg < 4; dg++) {
      short8 vb = *(const short8*)&vt_s[dg * 16 + l15][ks * 32 + lhi * 8];
      oacc[dg] = __builtin_amdgcn_mfma_f32_16x16x32_bf16(pa, vb, oacc[dg], 0, 0, 0);
    }
  }

  unsigned short* ob = aout + ((size_t)b * 4096 + qt * 64 + w * 16) * 768 + h * 64;
  #pragma unroll
  for (int dg = 0; dg < 4; dg++) {
    int d = dg * 16 + l15;
    #pragma unroll
    for (int r = 0; r < 4; r++) {
      ob[(size_t)(lhi * 4 + r) * 768 + d] = f2bf(oacc[dg][r] / sum[r]);
    }
  }
}

extern "C" void kernel_launch(void* const* d_in, const int* in_sizes, int n_in,
                              void* d_out, int out_size, void* d_ws, size_t ws_size,
                              hipStream_t stream) {
  const float* x   = (const float*)d_in[0];
  const float* Wq  = (const float*)d_in[1];
  const float* Wkv = (const float*)d_in[2];
  const float* srw = (const float*)d_in[3];
  const float* srb = (const float*)d_in[4];
  const float* lng = (const float*)d_in[5];
  const float* lnb = (const float*)d_in[6];
  const float* pw  = (const float*)d_in[7];
  const float* pb  = (const float*)d_in[8];

  char* ws = (char*)d_ws;
  float* qtab           = (float*)(ws);
  float* ktab           = (float*)(ws + 1048576);
  unsigned short* xb    = (unsigned short*)(ws + 1310720);    // bf16 x; attn_out later
  unsigned short* attno = xb;
  unsigned short* qrope = (unsigned short*)(ws + 13893632);
  unsigned short* part  = (unsigned short*)(ws + 26476544);   // [4][2048][768] bf16
  unsigned short* kr    = (unsigned short*)(ws + 26476544);   // overlays part (dead)
  unsigned short* vr    = (unsigned short*)(ws + 29622272);
  unsigned short* wqb   = (unsigned short*)(ws + 39059456);
  unsigned short* wkvb  = (unsigned short*)(ws + 40239104);
  unsigned short* pwb   = (unsigned short*)(ws + 42598400);
  unsigned short* wsrb  = (unsigned short*)(ws + 43778048);   // [4][768][768] bf16
  unsigned short* xrn   = (unsigned short*)(ws + 48496640);   // [2048][768] bf16

  k_prep<<<18304, 256, 0, stream>>>(x, Wq, Wkv, pw, srw, qtab, ktab,
                                    xb, wqb, wkvb, pwb, wsrb);
  k_g<2><<<768, 256, 0, stream>>>(xb, wqb, wsrb, qrope, part, nullptr, qtab);
  k_lnr<<<2048, 256, 0, stream>>>(part, srb, lng, lnb, xrn);
  k_g<1><<<192, 256, 0, stream>>>(xrn, wkvb, nullptr, kr, vr, nullptr, ktab);
  k_attn<<<dim3(64, 12, 2), 256, 0, stream>>>(qrope, kr, vr, attno);
  k_g<0><<<384, 256, 0, stream>>>(attno, pwb, nullptr, d_out, nullptr, pb, nullptr);
}

// Round 8
// 129.104 us; speedup vs baseline: 2.2151x; 1.0187x over previous
//
#include <hip/hip_runtime.h>
#include <hip/hip_bf16.h>
#include <math.h>

typedef __attribute__((ext_vector_type(4))) float f32x4;
typedef __attribute__((ext_vector_type(8))) short short8;
typedef __attribute__((ext_vector_type(8))) unsigned short ushort8;
typedef __attribute__((ext_vector_type(4))) unsigned short ushort4v;

__device__ __forceinline__ unsigned short f2bf(float f) {
  __hip_bfloat16 h = __float2bfloat16(f);
  return *reinterpret_cast<unsigned short*>(&h);
}
__device__ __forceinline__ float bf2f(unsigned short u) {
  unsigned v = ((unsigned)u) << 16;
  return *reinterpret_cast<float*>(&v);
}
__device__ __forceinline__ void async16(const void* g, void* l) {
  __builtin_amdgcn_global_load_lds(
      (__attribute__((address_space(1))) void*)g,
      (__attribute__((address_space(3))) void*)l, 16, 0, 0);
}
#define WAITVM8 { asm volatile("s_waitcnt vmcnt(8)" ::: "memory"); __builtin_amdgcn_sched_barrier(0); }
#define WAITVM4 { asm volatile("s_waitcnt vmcnt(4)" ::: "memory"); __builtin_amdgcn_sched_barrier(0); }
#define WAITVM0 { asm volatile("s_waitcnt vmcnt(0)" ::: "memory"); __builtin_amdgcn_sched_barrier(0); }

// ---------------- fused prep: RoPE tables + all f32->bf16 casts + sr_w repack ----------------
__global__ __launch_bounds__(256) void k_prep(
    const float* __restrict__ x, const float* __restrict__ Wq,
    const float* __restrict__ Wkv, const float* __restrict__ pw,
    const float* __restrict__ srw,
    float* __restrict__ qtab, float* __restrict__ ktab,
    unsigned short* __restrict__ xb, unsigned short* __restrict__ wqb,
    unsigned short* __restrict__ wkvb, unsigned short* __restrict__ pwb,
    unsigned short* __restrict__ wsrb)
{
  int idx = blockIdx.x * 256 + threadIdx.x;
  if (idx < 131072) {                       // q-table [4096][32]
    int n = idx >> 5, i = idx & 31;
    float freq = powf(10000.0f, -(float)(i >> 1) * (1.0f / 16.0f));
    float pos = (i & 1) ? (float)(n >> 6) : (float)(n & 63);
    float a = pos * freq;
    qtab[idx * 2] = cosf(a);
    qtab[idx * 2 + 1] = sinf(a);
  } else if (idx < 163840) {                // k-table [1024][32]
    int t = idx - 131072;
    int m = t >> 5, i = t & 31;
    float freq = powf(10000.0f, -(float)(i >> 1) * (1.0f / 16.0f));
    float pos = (i & 1) ? (0.5f + 2.0f * (float)(m >> 6)) : (0.5f + 2.0f * (float)(m & 63));
    float a = pos * freq;
    ktab[t * 2] = cosf(a);
    ktab[t * 2 + 1] = sinf(a);
  } else if (idx < 1736704) {               // x cvt (float4 units)
    int g = idx - 163840;
    float4 v = ((const float4*)x)[g];
    ushort4v o; o[0]=f2bf(v.x); o[1]=f2bf(v.y); o[2]=f2bf(v.z); o[3]=f2bf(v.w);
    *(ushort4v*)(xb + g * 4) = o;
  } else if (idx < 1884160) {               // Wq cvt
    int g = idx - 1736704;
    float4 v = ((const float4*)Wq)[g];
    ushort4v o; o[0]=f2bf(v.x); o[1]=f2bf(v.y); o[2]=f2bf(v.z); o[3]=f2bf(v.w);
    *(ushort4v*)(wqb + g * 4) = o;
  } else if (idx < 2179072) {               // Wkv cvt
    int g = idx - 1884160;
    float4 v = ((const float4*)Wkv)[g];
    ushort4v o; o[0]=f2bf(v.x); o[1]=f2bf(v.y); o[2]=f2bf(v.z); o[3]=f2bf(v.w);
    *(ushort4v*)(wkvb + g * 4) = o;
  } else if (idx < 2326528) {               // proj_w cvt
    int g = idx - 2179072;
    float4 v = ((const float4*)pw)[g];
    ushort4v o; o[0]=f2bf(v.x); o[1]=f2bf(v.y); o[2]=f2bf(v.z); o[3]=f2bf(v.w);
    *(ushort4v*)(pwb + g * 4) = o;
  } else if (idx < 4685824) {               // sr_w (O,C,2,2) -> [patch][O][C]
    int g = idx - 2326528;
    int o = g / 3072;
    int rem = g - o * 3072;
    int c = rem >> 2, patch = rem & 3;
    wsrb[(size_t)patch * 589824 + o * 768 + c] = f2bf(srw[g]);
  }
}

// ---------------- GEMM, 128x128 tile, BK=32, 4-buffer 3-ahead counted-vmcnt ----------------
// Deep prefetch: stage(kt) issued 3 steps early; wait vmcnt(8) keeps 2 stages in flight.
// MODE 0: proj  (384 blocks) : O0=f32 d_out (+bias), swapped-operand MFMA, coalesced stores
// MODE 1: kv    (192 blocks) : O0=kr (RoPE), O1=vr
// MODE 2: qconv (768 blocks) : tile<384 Q->O0=qrope (RoPE); else conv patch->O1=part (bf16)
template<int MODE>
__global__ __launch_bounds__(256) void k_g(
    const unsigned short* __restrict__ A, const unsigned short* __restrict__ W,
    const unsigned short* __restrict__ W2,
    void* __restrict__ O0, void* __restrict__ O1,
    const float* __restrict__ bias, const float* __restrict__ tab)
{
  __shared__ __align__(16) unsigned short As[4][128][32];   // 32 KB
  __shared__ __align__(16) unsigned short Ws[4][128][32];   // 32 KB
  const int tid = threadIdx.x, lane = tid & 63, wid = tid >> 6;
  const int wr = (wid >> 1) * 64, wc = (wid & 1) * 64;
  const int l15 = lane & 15, lhi = lane >> 4;
  const int K = 768, NT = 24;

  // XCD-chunked bijective swizzle (grid % 8 == 0 for all modes)
  const int NWG = (MODE == 2) ? 768 : (MODE == 1 ? 192 : 384);
  const int tile = ((int)blockIdx.x & 7) * (NWG >> 3) + ((int)blockIdx.x >> 3);

  int cm, cn, patch = 0;
  bool isconv = false;
  if (MODE == 2) {
    if (tile < 384) { cm = (tile / 6) * 128; cn = (tile % 6) * 128; }
    else {
      int c = tile - 384; isconv = true;
      patch = c / 96; int r = c - patch * 96;
      cm = (r / 6) * 128; cn = (r % 6) * 128;
    }
  } else if (MODE == 1) {
    cm = (tile / 12) * 128; cn = (tile % 12) * 128;
  } else {
    cm = (tile / 6) * 128; cn = (tile % 6) * 128;
  }

  size_t aoff0, aoff1;
  {
    int r0 = cm + wid * 32 + (lane >> 2);
    int r1 = r0 + 16;
    if (MODE == 2 && isconv) {
      int kh = patch >> 1, kw = patch & 1;
      int b0 = r0 >> 10, p0 = r0 & 1023;
      int b1 = r1 >> 10, p1 = r1 & 1023;
      r0 = b0 * 4096 + (2 * (p0 >> 5) + kh) * 64 + 2 * (p0 & 31) + kw;
      r1 = b1 * 4096 + (2 * (p1 >> 5) + kh) * 64 + 2 * (p1 & 31) + kw;
    }
    aoff0 = (size_t)r0 * K + (lane & 3) * 8;
    aoff1 = (size_t)r1 * K + (lane & 3) * 8;
  }
  const unsigned short* wbase = (MODE == 2 && isconv) ? (W2 + (size_t)patch * 589824) : W;
  size_t woff0 = (size_t)(cn + wid * 32 + (lane >> 2)) * K + (lane & 3) * 8;
  size_t woff1 = woff0 + (size_t)16 * K;

#define STAGE(bi, kt) { \
    async16(A + aoff0 + (kt) * 32,     &As[bi][wid * 32][0]);      \
    async16(A + aoff1 + (kt) * 32,     &As[bi][wid * 32 + 16][0]); \
    async16(wbase + woff0 + (kt) * 32, &Ws[bi][wid * 32][0]);      \
    async16(wbase + woff1 + (kt) * 32, &Ws[bi][wid * 32 + 16][0]); }

  f32x4 zero = {0.f, 0.f, 0.f, 0.f};
  f32x4 acc[4][4];
  #pragma unroll
  for (int i = 0; i < 4; i++)
    #pragma unroll
    for (int j = 0; j < 4; j++) acc[i][j] = zero;

  STAGE(0, 0);
  STAGE(1, 1);
  STAGE(2, 2);

  #pragma unroll 4
  for (int kt = 0; kt < NT; ++kt) {
    // stage(kt) must be landed; stages kt+1, kt+2 may stay in flight (4 asyncs each)
    if (kt + 2 < NT)      WAITVM8
    else if (kt + 1 < NT) WAITVM4
    else                  WAITVM0
    __builtin_amdgcn_s_barrier();            // all waves' stage(kt) landed; buf (kt+3)&3 free
    __builtin_amdgcn_sched_barrier(0);
    const int bi = kt & 3;
    if (kt + 3 < NT) STAGE((kt + 3) & 3, kt + 3);
    short8 af[4], wf[4];
    #pragma unroll
    for (int m = 0; m < 4; m++) af[m] = *(const short8*)&As[bi][wr + m * 16 + l15][lhi * 8];
    #pragma unroll
    for (int n = 0; n < 4; n++) wf[n] = *(const short8*)&Ws[bi][wc + n * 16 + l15][lhi * 8];
    #pragma unroll
    for (int m = 0; m < 4; m++)
      #pragma unroll
      for (int n = 0; n < 4; n++) {
        if (MODE == 0)
          acc[m][n] = __builtin_amdgcn_mfma_f32_16x16x32_bf16(wf[n], af[m], acc[m][n], 0, 0, 0);
        else
          acc[m][n] = __builtin_amdgcn_mfma_f32_16x16x32_bf16(af[m], wf[n], acc[m][n], 0, 0, 0);
      }
  }
#undef STAGE

  if (MODE == 0) {
    // swapped operands: acc[m][n] holds rows = A-rows (l15), 4 consecutive out-cols (lhi*4+r)
    float* O = (float*)O0;
    #pragma unroll
    for (int n = 0; n < 4; n++) {
      int colb = cn + wc + n * 16 + lhi * 4;
      f32x4 bv = *(const f32x4*)&bias[colb];
      #pragma unroll
      for (int m = 0; m < 4; m++) {
        int row = cm + wr + m * 16 + l15;
        f32x4 v = acc[m][n] + bv;
        *(f32x4*)&O[(size_t)row * 768 + colb] = v;
      }
    }
  } else if (MODE == 1) {
    // cols 0..767 -> K (RoPE), 768..1535 -> V
    unsigned short* kr = (unsigned short*)O0;
    unsigned short* vr = (unsigned short*)O1;
    const float2* t2 = (const float2*)tab;
    #pragma unroll
    for (int n = 0; n < 4; n++) {
      int col = cn + wc + n * 16 + l15;
      bool isk = (col < 768);
      int c2 = isk ? col : col - 768;
      int hh = c2 >> 6, d = c2 & 63, i = d >> 1;
      #pragma unroll
      for (int m = 0; m < 4; m++)
        #pragma unroll
        for (int r = 0; r < 4; r++) {
          int row = cm + wr + m * 16 + lhi * 4 + r;
          int bb = row >> 10, mm = row & 1023;
          float v = acc[m][n][r];
          float p = __shfl_xor(v, 1);
          size_t o = ((size_t)(bb * 12 + hh) * 1024 + mm) * 64 + d;
          if (isk) {
            float2 cs = t2[mm * 32 + i];
            float ov = (d & 1) ? (p * cs.y + v * cs.x) : (v * cs.x - p * cs.y);
            kr[o] = f2bf(ov);
          } else {
            vr[o] = f2bf(v);
          }
        }
    }
  } else {
    if (!isconv) {
      unsigned short* qr = (unsigned short*)O0;
      const float2* t2 = (const float2*)tab;
      #pragma unroll
      for (int n = 0; n < 4; n++) {
        int col = cn + wc + n * 16 + l15;
        int hh = col >> 6, d = col & 63, i = d >> 1;
        #pragma unroll
        for (int m = 0; m < 4; m++)
          #pragma unroll
          for (int r = 0; r < 4; r++) {
            int row = cm + wr + m * 16 + lhi * 4 + r;
            int bb = row >> 12, np = row & 4095;
            float v = acc[m][n][r];
            float p = __shfl_xor(v, 1);
            float2 cs = t2[np * 32 + i];
            float o = (d & 1) ? (p * cs.y + v * cs.x) : (v * cs.x - p * cs.y);
            qr[((size_t)(bb * 12 + hh) * 4096 + np) * 64 + d] = f2bf(o);
          }
      }
    } else {
      unsigned short* O = (unsigned short*)O1 + (size_t)patch * 2048 * 768;
      #pragma unroll
      for (int n = 0; n < 4; n++) {
        int col = cn + wc + n * 16 + l15;
        #pragma unroll
        for (int m = 0; m < 4; m++)
          #pragma unroll
          for (int r = 0; r < 4; r++) {
            int row = cm + wr + m * 16 + lhi * 4 + r;
            O[(size_t)row * 768 + col] = f2bf(acc[m][n][r]);
          }
      }
    }
  }
}

// ---------------- fused partial-reduce + bias + LayerNorm -> bf16 ----------------
__global__ __launch_bounds__(256) void k_lnr(const unsigned short* __restrict__ part,
    const float* __restrict__ srb, const float* __restrict__ g,
    const float* __restrict__ b, unsigned short* __restrict__ out) {
  int row = blockIdx.x;
  int t = threadIdx.x;
  float v[3];
  #pragma unroll
  for (int j = 0; j < 3; j++) {
    int c = t + j * 256;
    float s = srb[c];
    #pragma unroll
    for (int p = 0; p < 4; p++)
      s += bf2f(part[((size_t)p * 2048 + row) * 768 + c]);
    v[j] = s;
  }
  float s = v[0] + v[1] + v[2];
  float s2 = v[0] * v[0] + v[1] * v[1] + v[2] * v[2];
  #pragma unroll
  for (int off = 1; off < 64; off <<= 1) {
    s += __shfl_xor(s, off);
    s2 += __shfl_xor(s2, off);
  }
  __shared__ float ss[4], ss2[4];
  int w = t >> 6;
  if ((t & 63) == 0) { ss[w] = s; ss2[w] = s2; }
  __syncthreads();
  s = ss[0] + ss[1] + ss[2] + ss[3];
  s2 = ss2[0] + ss2[1] + ss2[2] + ss2[3];
  float mu = s * (1.0f / 768.0f);
  float var = s2 * (1.0f / 768.0f) - mu * mu;
  float rstd = rsqrtf(var + 1e-5f);
  unsigned short* o = out + (size_t)row * 768;
  #pragma unroll
  for (int j = 0; j < 3; j++) {
    int c = t + j * 256;
    o[c] = f2bf((v[j] - mu) * rstd * g[c] + b[c]);
  }
}

// ---------------- masked attention: per (b,h,64-query tile), bf16 out ----------------
__global__ __launch_bounds__(256) void k_attn(
    const unsigned short* __restrict__ qr,
    const unsigned short* __restrict__ kr,
    const unsigned short* __restrict__ vr,
    unsigned short* __restrict__ aout)
{
  __shared__ __align__(16) unsigned short kt_s[96][72];
  __shared__ __align__(16) unsigned short vt_s[64][104];
  __shared__ __align__(16) unsigned short p_s[4][16][104];

  const int qt = blockIdx.x;
  const int h = blockIdx.y;
  const int b = blockIdx.z;
  const int bh = b * 12 + h;
  const int tid = threadIdx.x, lane = tid & 63, w = tid >> 6;
  const int l15 = lane & 15, lhi = lane >> 4;

  const unsigned short* kg = kr + (size_t)bh * 1024 * 64;
  #pragma unroll
  for (int it = 0; it < 3; it++) {
    int ch = it * 256 + tid;
    int row = ch >> 3, c8 = (ch & 7) * 8;
    *(ushort8*)&kt_s[row][c8] = *(const ushort8*)(kg + row * 64 + c8);
  }
  const unsigned short* vg = vr + (size_t)bh * 1024 * 64;
  #pragma unroll
  for (int it = 0; it < 24; it++) {
    int e = it * 256 + tid;
    int row = e >> 6, d = e & 63;
    vt_s[d][row] = vg[row * 64 + d];
  }
  __syncthreads();

  const unsigned short* qg = qr + (size_t)bh * 4096 * 64
                           + (size_t)(qt * 64 + w * 16 + l15) * 64 + lhi * 8;
  short8 qf0 = *(const short8*)qg;
  short8 qf1 = *(const short8*)(qg + 32);

  f32x4 zero = {0.f, 0.f, 0.f, 0.f};
  f32x4 sacc[6];
  #pragma unroll
  for (int g = 0; g < 6; g++) sacc[g] = zero;
  #pragma unroll
  for (int g = 0; g < 6; g++) {
    short8 kf0 = *(const short8*)&kt_s[g * 16 + l15][lhi * 8];
    short8 kf1 = *(const short8*)&kt_s[g * 16 + l15][32 + lhi * 8];
    sacc[g] = __builtin_amdgcn_mfma_f32_16x16x32_bf16(qf0, kf0, sacc[g], 0, 0, 0);
    sacc[g] = __builtin_amdgcn_mfma_f32_16x16x32_bf16(qf1, kf1, sacc[g], 0, 0, 0);
  }

  int visv[4];
  #pragma unroll
  for (int r = 0; r < 4; r++) {
    int n = qt * 64 + w * 16 + lhi * 4 + r;
    visv[r] = 2 * (n >> 7) + (((n >> 6) + ((n & 63) << 6)) >> 7) + 1;
  }

  float mx[4] = {-INFINITY, -INFINITY, -INFINITY, -INFINITY};
  #pragma unroll
  for (int g = 0; g < 6; g++) {
    int key = g * 16 + l15;
    #pragma unroll
    for (int r = 0; r < 4; r++) {
      float s = (key < visv[r]) ? sacc[g][r] * 0.125f : -INFINITY;
      sacc[g][r] = s;
      mx[r] = fmaxf(mx[r], s);
    }
  }
  #pragma unroll
  for (int off = 1; off < 16; off <<= 1) {
    #pragma unroll
    for (int r = 0; r < 4; r++) mx[r] = fmaxf(mx[r], __shfl_xor(mx[r], off));
  }
  float sum[4] = {0.f, 0.f, 0.f, 0.f};
  #pragma unroll
  for (int g = 0; g < 6; g++) {
    #pragma unroll
    for (int r = 0; r < 4; r++) {
      float pv = __expf(sacc[g][r] - mx[r]);
      sum[r] += pv;
      p_s[w][lhi * 4 + r][g * 16 + l15] = f2bf(pv);
    }
  }
  #pragma unroll
  for (int off = 1; off < 16; off <<= 1) {
    #pragma unroll
    for (int r = 0; r < 4; r++) sum[r] += __shfl_xor(sum[r], off);
  }
  __syncthreads();

  f32x4 oacc[4];
  #pragma unroll
  for (int dg = 0; dg < 4; dg++) oacc[dg] = zero;
  #pragma unroll
  for (int ks = 0; ks < 3; ks++) {
    short8 pa = *(const short8*)&p_s[w][l15][ks * 32 + lhi * 8];
    #pragma unroll
    for (int dg = 0; dg < 4; dg++) {
      short8 vb = *(const short8*)&vt_s[dg * 16 + l15][ks * 32 + lhi * 8];
      oacc[dg] = __builtin_amdgcn_mfma_f32_16x16x32_bf16(pa, vb, oacc[dg], 0, 0, 0);
    }
  }

  unsigned short* ob = aout + ((size_t)b * 4096 + qt * 64 + w * 16) * 768 + h * 64;
  #pragma unroll
  for (int dg = 0; dg < 4; dg++) {
    int d = dg * 16 + l15;
    #pragma unroll
    for (int r = 0; r < 4; r++) {
      ob[(size_t)(lhi * 4 + r) * 768 + d] = f2bf(oacc[dg][r] / sum[r]);
    }
  }
}

extern "C" void kernel_launch(void* const* d_in, const int* in_sizes, int n_in,
                              void* d_out, int out_size, void* d_ws, size_t ws_size,
                              hipStream_t stream) {
  const float* x   = (const float*)d_in[0];
  const float* Wq  = (const float*)d_in[1];
  const float* Wkv = (const float*)d_in[2];
  const float* srw = (const float*)d_in[3];
  const float* srb = (const float*)d_in[4];
  const float* lng = (const float*)d_in[5];
  const float* lnb = (const float*)d_in[6];
  const float* pw  = (const float*)d_in[7];
  const float* pb  = (const float*)d_in[8];

  char* ws = (char*)d_ws;
  float* qtab           = (float*)(ws);
  float* ktab           = (float*)(ws + 1048576);
  unsigned short* xb    = (unsigned short*)(ws + 1310720);    // bf16 x; attn_out later
  unsigned short* attno = xb;
  unsigned short* qrope = (unsigned short*)(ws + 13893632);
  unsigned short* part  = (unsigned short*)(ws + 26476544);   // [4][2048][768] bf16
  unsigned short* kr    = (unsigned short*)(ws + 26476544);   // overlays part (dead)
  unsigned short* vr    = (unsigned short*)(ws + 29622272);
  unsigned short* wqb   = (unsigned short*)(ws + 39059456);
  unsigned short* wkvb  = (unsigned short*)(ws + 40239104);
  unsigned short* pwb   = (unsigned short*)(ws + 42598400);
  unsigned short* wsrb  = (unsigned short*)(ws + 43778048);   // [4][768][768] bf16
  unsigned short* xrn   = (unsigned short*)(ws + 48496640);   // [2048][768] bf16

  k_prep<<<18304, 256, 0, stream>>>(x, Wq, Wkv, pw, srw, qtab, ktab,
                                    xb, wqb, wkvb, pwb, wsrb);
  k_g<2><<<768, 256, 0, stream>>>(xb, wqb, wsrb, qrope, part, nullptr, qtab);
  k_lnr<<<2048, 256, 0, stream>>>(part, srb, lng, lnb, xrn);
  k_g<1><<<192, 256, 0, stream>>>(xrn, wkvb, nullptr, kr, vr, nullptr, ktab);
  k_attn<<<dim3(64, 12, 2), 256, 0, stream>>>(qrope, kr, vr, attno);
  k_g<0><<<384, 256, 0, stream>>>(attno, pwb, nullptr, d_out, nullptr, pb, nullptr);
}